// Round 8
// baseline (1255.824 us; speedup 1.0000x reference)
//
#include <hip/hip_runtime.h>
#include <stdint.h>

#define N_NODES 50000
#define N_EDGES 400000
#define NBLK_SC 196        // ceil(50000/256)
#define MT      782        // ceil(50000/64) m-tiles

typedef unsigned short u16;

__device__ __forceinline__ float b2f(u16 u){ unsigned int x=((unsigned int)u)<<16; float f; __builtin_memcpy(&f,&x,4); return f; }
__device__ __forceinline__ u16 f2b(float f){ unsigned int x; __builtin_memcpy(&x,&f,4); x += 0x7fffu + ((x>>16)&1u); return (u16)(x>>16); }

// ---------------- utility ----------------
__global__ void k_zeroi(int* __restrict__ p, int n){
  int i = blockIdx.x*256+threadIdx.x;
  if (i < n) p[i] = 0;
}
__global__ void k_fillf(float* __restrict__ p, int n, float v){
  int i = blockIdx.x*256+threadIdx.x;
  if (i < n) p[i] = v;
}
// Wt[n*K+k] = W[k*Nc+n], fp32 -> fp32, zero-pad n in [Nc,Npad)
__global__ void k_transpose_f(const float* __restrict__ W, float* __restrict__ Wt, int K, int Nc, int Npad){
  int i = blockIdx.x*256+threadIdx.x;
  if (i >= Npad*K) return;
  int n = i / K, k = i - n*K;
  Wt[i] = (n < Nc) ? W[k*Nc + n] : 0.f;
}
// probes
__global__ void k_diag_nz(const u16* __restrict__ buf, int n, int stride, int* __restrict__ slot){
  int i = (blockIdx.x*256+threadIdx.x) * stride;
  if (i < n){ u16 v = buf[i]; if (v & 0x7fffu) atomicOr(slot, 1); }
}
__global__ void k_diag_ro(const int* __restrict__ ro, int* __restrict__ slot){
  if (threadIdx.x==0 && blockIdx.x==0 && ro[N_NODES]==N_EDGES) atomicOr(slot, 1);
}
// override output ONLY if x4 sampled all-zero: dv encodes stage health
__global__ void k_diag_end(const int* __restrict__ flag, float* __restrict__ out){
  int i = blockIdx.x*256+threadIdx.x;
  if (i >= N_NODES*32) return;
  if (flag[4] != 0) return;   // x4 alive -> keep real output
  float dv = 100.f + (flag[0]?4.f:0.f) + (flag[1]?8.f:0.f) + (flag[2]?16.f:0.f)
           + (flag[3]?32.f:0.f);
  out[i] = dv;
}

// ---------------- CSR build ----------------
__global__ void k_count(const int* __restrict__ dst, int* __restrict__ cnt){
  int e = blockIdx.x*256+threadIdx.x;
  if (e < N_EDGES) atomicAdd(&cnt[dst[e]], 1);
}
__global__ void k_scan1(const int* __restrict__ cnt, int* __restrict__ ro, int* __restrict__ bsums){
  __shared__ int sm[256];
  int b = blockIdx.x, t = threadIdx.x, i = b*256+t;
  int v = (i < N_NODES) ? cnt[i] : 0;
  sm[t] = v; __syncthreads();
  for (int off=1; off<256; off<<=1){
    int x = 0; if (t>=off) x = sm[t-off];
    __syncthreads();
    if (t>=off) sm[t] += x;
    __syncthreads();
  }
  if (i < N_NODES) ro[i] = sm[t]-v;
  if (t==255) bsums[b] = sm[255];
}
__global__ void k_scan2(int* __restrict__ bsums, int nb){
  __shared__ int sm[256];
  int t = threadIdx.x;
  int v = (t<nb) ? bsums[t] : 0;
  sm[t]=v; __syncthreads();
  for (int off=1; off<256; off<<=1){
    int x = 0; if (t>=off) x = sm[t-off];
    __syncthreads();
    if (t>=off) sm[t] += x;
    __syncthreads();
  }
  if (t<nb) bsums[t] = sm[t]-v;
}
__global__ void k_scan3(int* __restrict__ ro, const int* __restrict__ bsums){
  int b = blockIdx.x, t = threadIdx.x, i = b*256+t;
  if (i < N_NODES) ro[i] += bsums[b];
  if (i == 0) ro[N_NODES] = N_EDGES;
}
__global__ void k_scatter(const int* __restrict__ src, const int* __restrict__ dst,
                          const int* __restrict__ ro, int* __restrict__ cursor,
                          int* __restrict__ perm, int* __restrict__ pdst){
  int e = blockIdx.x*256+threadIdx.x;
  if (e >= N_EDGES) return;
  int d = dst[e];
  int pos = ro[d] + atomicAdd(&cursor[d], 1);
  perm[pos] = src[e];
  pdst[pos] = d;
}

// ---------------- VALU GEMM: C[N x Nst] = A[N x K] @ Wt^T + bias, C bf16 ----------------
// Wt is [Npad x K] fp32 (pre-transposed). 64x64 tile, 4x4 register blocking.
__global__ __launch_bounds__(256)
void k_gemm_f32A(const float* __restrict__ A, const float* __restrict__ Wt,
                 const float* __restrict__ bias, u16* __restrict__ C,
                 int K, int Nst, int nTiles, int* __restrict__ ran)
{
  if (ran && threadIdx.x==0 && blockIdx.x==0) atomicOr(ran, 1);
  __shared__ float sA[64][33];
  __shared__ float sW[64][33];
  int t = threadIdx.x;
  int mTile = blockIdx.x / nTiles, nTile = blockIdx.x - mTile*nTiles;
  int mBase = mTile*64, nBase = nTile*64;
  int tr = t >> 4, tc = t & 15;
  int r0 = tr*4, c0 = tc*4;
  float acc[4][4] = {};
  for (int k0=0; k0<K; k0+=32){
    #pragma unroll
    for (int it=0; it<8; ++it){
      int idx = it*256 + t;
      int m = idx >> 5, kk = idx & 31;
      int row = mBase + m;
      sA[m][kk] = (row < N_NODES) ? A[(size_t)row*K + k0+kk] : 0.f;
      sW[m][kk] = Wt[(size_t)(nBase+m)*K + k0+kk];
    }
    __syncthreads();
    for (int kk=0; kk<32; ++kk){
      float a0=sA[r0+0][kk], a1=sA[r0+1][kk], a2=sA[r0+2][kk], a3=sA[r0+3][kk];
      float w0=sW[c0+0][kk], w1=sW[c0+1][kk], w2=sW[c0+2][kk], w3=sW[c0+3][kk];
      acc[0][0]+=a0*w0; acc[0][1]+=a0*w1; acc[0][2]+=a0*w2; acc[0][3]+=a0*w3;
      acc[1][0]+=a1*w0; acc[1][1]+=a1*w1; acc[1][2]+=a1*w2; acc[1][3]+=a1*w3;
      acc[2][0]+=a2*w0; acc[2][1]+=a2*w1; acc[2][2]+=a2*w2; acc[2][3]+=a2*w3;
      acc[3][0]+=a3*w0; acc[3][1]+=a3*w1; acc[3][2]+=a3*w2; acc[3][3]+=a3*w3;
    }
    __syncthreads();
  }
  #pragma unroll
  for (int i=0;i<4;i++){
    int mm = mBase + r0 + i;
    if (mm >= N_NODES) continue;
    #pragma unroll
    for (int j=0;j<4;j++){
      int nn = nBase + c0 + j;
      float v = acc[i][j];
      if (bias) v += bias[nn];
      C[(size_t)mm*Nst + nn] = f2b(v);
    }
  }
}

__global__ __launch_bounds__(256)
void k_gemm_bf16A(const u16* __restrict__ A, const float* __restrict__ Wt,
                  const float* __restrict__ bias, u16* __restrict__ C,
                  int K, int Nst, int nTiles)
{
  __shared__ float sA[64][33];
  __shared__ float sW[64][33];
  int t = threadIdx.x;
  int mTile = blockIdx.x / nTiles, nTile = blockIdx.x - mTile*nTiles;
  int mBase = mTile*64, nBase = nTile*64;
  int tr = t >> 4, tc = t & 15;
  int r0 = tr*4, c0 = tc*4;
  float acc[4][4] = {};
  for (int k0=0; k0<K; k0+=32){
    #pragma unroll
    for (int it=0; it<8; ++it){
      int idx = it*256 + t;
      int m = idx >> 5, kk = idx & 31;
      int row = mBase + m;
      sA[m][kk] = (row < N_NODES) ? b2f(A[(size_t)row*K + k0+kk]) : 0.f;
      sW[m][kk] = Wt[(size_t)(nBase+m)*K + k0+kk];
    }
    __syncthreads();
    for (int kk=0; kk<32; ++kk){
      float a0=sA[r0+0][kk], a1=sA[r0+1][kk], a2=sA[r0+2][kk], a3=sA[r0+3][kk];
      float w0=sW[c0+0][kk], w1=sW[c0+1][kk], w2=sW[c0+2][kk], w3=sW[c0+3][kk];
      acc[0][0]+=a0*w0; acc[0][1]+=a0*w1; acc[0][2]+=a0*w2; acc[0][3]+=a0*w3;
      acc[1][0]+=a1*w0; acc[1][1]+=a1*w1; acc[1][2]+=a1*w2; acc[1][3]+=a1*w3;
      acc[2][0]+=a2*w0; acc[2][1]+=a2*w1; acc[2][2]+=a2*w2; acc[2][3]+=a2*w3;
      acc[3][0]+=a3*w0; acc[3][1]+=a3*w1; acc[3][2]+=a3*w2; acc[3][3]+=a3*w3;
    }
    __syncthreads();
  }
  #pragma unroll
  for (int i=0;i<4;i++){
    int mm = mBase + r0 + i;
    if (mm >= N_NODES) continue;
    #pragma unroll
    for (int j=0;j<4;j++){
      int nn = nBase + c0 + j;
      float v = acc[i][j];
      if (bias) v += bias[nn];
      C[(size_t)mm*Nst + nn] = f2b(v);
    }
  }
}

// ---------------- row-dots (thread-serial) ----------------
__global__ __launch_bounds__(256)
void k_rowdot_cew(const u16* __restrict__ hb, const float* __restrict__ att, float* __restrict__ s){
  int n = blockIdx.x*256+threadIdx.x;
  if (n >= N_NODES) return;
  const u16* hp = hb + (size_t)n*128;
  float acc = 0.f;
  #pragma unroll 8
  for (int c=0;c<128;++c) acc += b2f(hp[c])*att[c];
  s[n] = acc;
}
__global__ __launch_bounds__(256)
void k_rowdot4(const u16* __restrict__ hb, const float* __restrict__ attS, const float* __restrict__ attD,
               float* __restrict__ aS, float* __restrict__ aD){
  int t = blockIdx.x*256+threadIdx.x;
  if (t >= N_NODES*4) return;
  int n = t>>2, h = t&3;
  const u16* hp = hb + (size_t)n*256 + h*64;
  const float* as = attS + h*64;
  const float* ad = attD + h*64;
  float ps=0.f, pd=0.f;
  #pragma unroll 8
  for (int c=0;c<64;++c){ float v=b2f(hp[c]); ps += v*as[c]; pd += v*ad[c]; }
  aS[t]=ps; aD[t]=pd;
}
__global__ __launch_bounds__(256)
void k_rowdot2(const u16* __restrict__ hb, const float* __restrict__ attS, const float* __restrict__ attD,
               float* __restrict__ aS, float* __restrict__ aD){
  int t = blockIdx.x*256+threadIdx.x;
  if (t >= N_NODES*4) return;
  int n = t>>2, h = t&3;
  const u16* hp = hb + (size_t)n*128 + h*32;
  const float* as = attS + h*32;
  const float* ad = attD + h*32;
  float ps=0.f, pd=0.f;
  #pragma unroll 8
  for (int c=0;c<32;++c){ float v=b2f(hp[c]); ps += v*as[c]; pd += v*ad[c]; }
  aS[t]=ps; aD[t]=pd;
}

// ---------------- aggregation (wave per node; serial redundant max) ----------------
__global__ __launch_bounds__(256)
void k_agg_cew(const u16* __restrict__ h0, const float* __restrict__ s, const float* __restrict__ cewf,
               const int* __restrict__ ro, const int* __restrict__ perm, u16* __restrict__ x1)
{
  int wave = threadIdx.x>>6, lane = threadIdx.x&63;
  int node = blockIdx.x*4 + wave;
  if (node >= N_NODES) return;
  float sd = s[node], cd = cewf[node];
  int beg = ro[node], end = ro[node+1];
  float m = -INFINITY;
  for (int j=beg; j<end; ++j){
    int u = perm[j];
    float a = s[u] + sd; a = a>=0.f ? a : 0.01f*a;
    a *= (cewf[u] + cd);
    m = fmaxf(m, a);
  }
  float den = 0.f, a0 = 0.f, a1 = 0.f;
  int f = 2*lane;
  for (int j=beg; j<end; ++j){
    int u = perm[j];
    float a = s[u] + sd; a = a>=0.f ? a : 0.01f*a;
    a *= (cewf[u] + cd);
    float w = __expf(a - m);
    den += w;
    unsigned int pv = *(const unsigned int*)(h0 + (size_t)u*128 + f);
    a0 += w * b2f((u16)(pv & 0xffffu));
    a1 += w * b2f((u16)(pv >> 16));
  }
  float inv = 1.f/(den + 1e-16f);
  float o0 = a0*inv; o0 = o0>0.f?o0:0.f;
  float o1 = a1*inv; o1 = o1>0.f?o1:0.f;
  *(unsigned int*)(x1 + (size_t)node*128 + f) = (unsigned int)f2b(o0) | ((unsigned int)f2b(o1)<<16);
}

template<int C, int F>
__global__ __launch_bounds__(256)
void k_agg_gat(const u16* __restrict__ hb, const float* __restrict__ aS, const float* __restrict__ aD,
               const float* __restrict__ bias, const int* __restrict__ ro, const int* __restrict__ perm,
               u16* __restrict__ out)
{
  int wave = threadIdx.x>>6, lane = threadIdx.x&63;
  int node = blockIdx.x*4 + wave;
  if (node >= N_NODES) return;
  auto lk = [](float x){ return x>=0.f ? x : 0.2f*x; };
  float ad0=aD[node*4+0], ad1=aD[node*4+1], ad2=aD[node*4+2], ad3=aD[node*4+3];
  float sl0=lk(aS[node*4+0]+ad0), sl1=lk(aS[node*4+1]+ad1),
        sl2=lk(aS[node*4+2]+ad2), sl3=lk(aS[node*4+3]+ad3);   // self-loop logits
  int beg = ro[node], end = ro[node+1];
  float m0=sl0, m1=sl1, m2=sl2, m3=sl3;
  for (int j=beg; j<end; ++j){
    int u = perm[j];
    m0 = fmaxf(m0, lk(aS[u*4+0]+ad0));
    m1 = fmaxf(m1, lk(aS[u*4+1]+ad1));
    m2 = fmaxf(m2, lk(aS[u*4+2]+ad2));
    m3 = fmaxf(m3, lk(aS[u*4+3]+ad3));
  }
  constexpr int CH = F/128;
  float ax[CH], ay[CH];
  int hd[CH];
  #pragma unroll
  for (int c=0;c<CH;++c){ ax[c]=0.f; ay[c]=0.f; hd[c] = (c*128 + 2*lane)/C; }
  float d0=0.f,d1=0.f,d2=0.f,d3=0.f;
  {
    float w0=__expf(sl0-m0), w1=__expf(sl1-m1), w2=__expf(sl2-m2), w3=__expf(sl3-m3);
    d0+=w0; d1+=w1; d2+=w2; d3+=w3;
    #pragma unroll
    for (int c=0;c<CH;++c){
      int f = c*128 + 2*lane;
      float ws = hd[c]==0?w0 : hd[c]==1?w1 : hd[c]==2?w2 : w3;
      unsigned int pv = *(const unsigned int*)(hb + (size_t)node*F + f);
      ax[c] += ws * b2f((u16)(pv & 0xffffu));
      ay[c] += ws * b2f((u16)(pv >> 16));
    }
  }
  for (int j=beg; j<end; ++j){
    int u = perm[j];
    float e0=__expf(lk(aS[u*4+0]+ad0)-m0), e1=__expf(lk(aS[u*4+1]+ad1)-m1),
          e2=__expf(lk(aS[u*4+2]+ad2)-m2), e3=__expf(lk(aS[u*4+3]+ad3)-m3);
    d0+=e0; d1+=e1; d2+=e2; d3+=e3;
    #pragma unroll
    for (int c=0;c<CH;++c){
      int f = c*128 + 2*lane;
      float we = hd[c]==0?e0 : hd[c]==1?e1 : hd[c]==2?e2 : e3;
      unsigned int pv = *(const unsigned int*)(hb + (size_t)u*F + f);
      ax[c] += we * b2f((u16)(pv & 0xffffu));
      ay[c] += we * b2f((u16)(pv >> 16));
    }
  }
  #pragma unroll
  for (int c=0;c<CH;++c){
    int f = c*128 + 2*lane;
    float dd = (hd[c]==0?d0 : hd[c]==1?d1 : hd[c]==2?d2 : d3) + 1e-16f;
    float ox = ax[c]/dd + bias[f];   ox = ox>0.f?ox:0.f;
    float oy = ay[c]/dd + bias[f+1]; oy = oy>0.f?oy:0.f;
    *(unsigned int*)(out + (size_t)node*F + f) = (unsigned int)f2b(ox) | ((unsigned int)f2b(oy)<<16);
  }
}

// ---------------- transformer conv ----------------
__global__ __launch_bounds__(256)
void k_tr_logits(const u16* __restrict__ qb, const u16* __restrict__ kb,
                 const int* __restrict__ perm, const int* __restrict__ pdst,
                 float* __restrict__ tlog)
{
  int t = blockIdx.x*256+threadIdx.x;
  if (t >= N_EDGES*4) return;
  int j = t>>2, h = t&3;
  int u = perm[j], d = pdst[j];
  const u16* qp = qb + (size_t)d*256 + h*64;
  const u16* kp = kb + (size_t)u*256 + h*64;
  float p = 0.f;
  #pragma unroll 8
  for (int c=0;c<64;++c) p += b2f(qp[c])*b2f(kp[c]);
  tlog[t] = p * 0.125f;
}
__global__ __launch_bounds__(256)
void k_tr_max(const int* __restrict__ ro, const float* __restrict__ tlog, float* __restrict__ mbuf)
{
  int t = blockIdx.x*256+threadIdx.x;
  if (t >= N_NODES*4) return;
  int n = t>>2, h = t&3;
  float m = -INFINITY;
  for (int j=ro[n]; j<ro[n+1]; ++j) m = fmaxf(m, tlog[j*4+h]);
  mbuf[t] = m;
}
__global__ __launch_bounds__(256)
void k_trans2(const u16* __restrict__ vb, const u16* __restrict__ skipb,
              const int* __restrict__ ro, const int* __restrict__ perm,
              const float* __restrict__ tlog, const float* __restrict__ mbuf, u16* __restrict__ x4)
{
  int wave = threadIdx.x>>6, lane = threadIdx.x&63;
  int node = blockIdx.x*4 + wave;
  if (node >= N_NODES) return;
  float m0=mbuf[node*4+0], m1=mbuf[node*4+1], m2=mbuf[node*4+2], m3=mbuf[node*4+3];
  float d0=0.f,d1=0.f,d2=0.f,d3=0.f, a0=0.f,a1=0.f,a2=0.f,a3=0.f;
  int beg = ro[node], end = ro[node+1];
  for (int j=beg; j<end; ++j){
    int u = perm[j];
    const size_t vbase = (size_t)u*256;
    float e0=__expf(tlog[j*4+0]-m0), e1=__expf(tlog[j*4+1]-m1),
          e2=__expf(tlog[j*4+2]-m2), e3=__expf(tlog[j*4+3]-m3);
    d0+=e0; d1+=e1; d2+=e2; d3+=e3;
    a0 += e0*b2f(vb[vbase+lane]);     a1 += e1*b2f(vb[vbase+64+lane]);
    a2 += e2*b2f(vb[vbase+128+lane]); a3 += e3*b2f(vb[vbase+192+lane]);
  }
  float o = 0.25f*( a0/(d0+1e-16f) + a1/(d1+1e-16f) + a2/(d2+1e-16f) + a3/(d3+1e-16f) );
  o += b2f(skipb[(size_t)node*128 + lane]);
  o = o>0.f ? o : 0.f;
  x4[(size_t)node*64 + lane] = f2b(o);
}

// ---------------- final linear 64 -> 32, fp32 out ----------------
__global__ __launch_bounds__(256)
void k_final(const u16* __restrict__ x4, const float* __restrict__ Wf, const float* __restrict__ bf,
             float* __restrict__ out)
{
  int i = blockIdx.x*256+threadIdx.x;
  if (i >= N_NODES*32) return;
  int n = i>>5, c = i&31;
  const u16* xr = x4 + (size_t)n*64;
  float acc = 0.f;
  #pragma unroll
  for (int k=0;k<64;++k) acc += b2f(xr[k]) * Wf[k*32+c];
  acc += bf[c];
  out[i] = acc;
}

// ---------------- host ----------------
extern "C" void kernel_launch(void* const* d_in, const int* in_sizes, int n_in,
                              void* d_out, int out_size, void* d_ws, size_t ws_size,
                              hipStream_t stream)
{
  const float* i_x    = (const float*)d_in[0];
  const int*   i_ei   = (const int*)d_in[1];
  const float* i_cew  = (const float*)d_in[2];
  const float* i_cewW = (const float*)d_in[3];
  const float* i_cewB = (const float*)d_in[4];
  const float* i_cewA = (const float*)d_in[5];
  const float* i_W1   = (const float*)d_in[6];
  const float* i_aS1  = (const float*)d_in[7];
  const float* i_aD1  = (const float*)d_in[8];
  const float* i_b1   = (const float*)d_in[9];
  const float* i_W2   = (const float*)d_in[10];
  const float* i_aS2  = (const float*)d_in[11];
  const float* i_aD2  = (const float*)d_in[12];
  const float* i_b2   = (const float*)d_in[13];
  const float* i_Wq   = (const float*)d_in[14];
  const float* i_bq   = (const float*)d_in[15];
  const float* i_Wk   = (const float*)d_in[16];
  const float* i_bk   = (const float*)d_in[17];
  const float* i_Wv   = (const float*)d_in[18];
  const float* i_bv   = (const float*)d_in[19];
  const float* i_Wsk  = (const float*)d_in[20];
  const float* i_bsk  = (const float*)d_in[21];
  const float* i_Wf   = (const float*)d_in[22];
  const float* i_bf   = (const float*)d_in[23];
  (void)in_sizes; (void)n_in; (void)out_size;

  char* w = (char*)d_ws;
  size_t off = 0;
  auto A = [&](size_t bytes)->char*{ char* p = w + off; off = (off + bytes + 255) & ~(size_t)255; return p; };

  int*   flag   = (int*)A(256);          // [0]CSR [1]gemmRan [2]h0 [3]x3 [4]x4
  int*   bsums  = (int*)A(1024);
  float* sbuf   = (float*)A((size_t)N_NODES*4);
  float* aS     = (float*)A((size_t)N_NODES*16);
  float* aD     = (float*)A((size_t)N_NODES*16);
  float* mbuf   = (float*)A((size_t)N_NODES*16);
  int*   cnt    = (int*)A((size_t)N_NODES*4);
  int*   ro     = (int*)A((size_t)(N_NODES+1)*4);
  int*   cursor = (int*)A((size_t)N_NODES*4);
  int*   perm   = (int*)A((size_t)N_EDGES*4);
  int*   pdst   = (int*)A((size_t)N_EDGES*4);
  float* tlog   = (float*)A((size_t)N_EDGES*16);
  float* cewWt  = (float*)A(128*128*4);
  float* W1t    = (float*)A(256*128*4);
  float* W2t    = (float*)A(128*256*4);
  float* Wqt    = (float*)A(256*128*4);
  float* Wkt    = (float*)A(256*128*4);
  float* Wvt    = (float*)A(256*128*4);
  float* Wskt   = (float*)A(128*128*4);
  u16* S1 = (u16*)A((size_t)N_NODES*128*2);   // h0 -> h2 -> skipb
  u16* S2 = (u16*)A((size_t)N_NODES*128*2);   // x1 -> x3
  u16* G1 = (u16*)A((size_t)N_NODES*256*2);   // h1 -> qb -> vb
  u16* G2 = (u16*)A((size_t)N_NODES*256*2);   // x2 -> kb -> x4
  size_t need = off;

  float* outf = (float*)d_out;

  // first launch: canary (distinguishes "nothing ran" from later failures)
  k_fillf<<<(N_NODES*32+255)/256,256,0,stream>>>(outf, N_NODES*32, 999.f);

  if (ws_size < need){
    k_fillf<<<(N_NODES*32+255)/256,256,0,stream>>>(outf, N_NODES*32,
        8192.f + 32.f * (float)((ws_size >> 20) > 255 ? 255 : (ws_size >> 20)));
    return;
  }

  u16* h0 = S1;  u16* x1 = S2;
  u16* h1 = G1;  u16* x2 = G2;
  u16* h2 = S1;  u16* x3 = S2;
  u16* qb = G1;  u16* kb = G2;
  u16* vb = G1;  u16* skipb = S1;  u16* x4 = G2;

  k_zeroi<<<1,256,0,stream>>>(flag, 8);
  k_zeroi<<<(N_NODES+255)/256,256,0,stream>>>(cnt, N_NODES);
  k_zeroi<<<(N_NODES+255)/256,256,0,stream>>>(cursor, N_NODES);

  // weight transposes (fp32 -> fp32)
  k_transpose_f<<<(128*128+255)/256,256,0,stream>>>(i_cewW, cewWt, 128, 128, 128);
  k_transpose_f<<<(256*128+255)/256,256,0,stream>>>(i_W1,   W1t,  128, 256, 256);
  k_transpose_f<<<(128*256+255)/256,256,0,stream>>>(i_W2,   W2t,  256, 128, 128);
  k_transpose_f<<<(256*128+255)/256,256,0,stream>>>(i_Wq,   Wqt,  128, 256, 256);
  k_transpose_f<<<(256*128+255)/256,256,0,stream>>>(i_Wk,   Wkt,  128, 256, 256);
  k_transpose_f<<<(256*128+255)/256,256,0,stream>>>(i_Wv,   Wvt,  128, 256, 256);
  k_transpose_f<<<(128*128+255)/256,256,0,stream>>>(i_Wsk,  Wskt, 128, 64, 128);

  // CSR by destination
  k_count<<<(N_EDGES+255)/256,256,0,stream>>>(i_ei + N_EDGES, cnt);
  k_scan1<<<NBLK_SC,256,0,stream>>>(cnt, ro, bsums);
  k_scan2<<<1,256,0,stream>>>(bsums, NBLK_SC);
  k_scan3<<<NBLK_SC,256,0,stream>>>(ro, bsums);
  k_scatter<<<(N_EDGES+255)/256,256,0,stream>>>(i_ei, i_ei + N_EDGES, ro, cursor, perm, pdst);
  k_diag_ro<<<1,64,0,stream>>>(ro, flag + 0);

  const int NAGG = (N_NODES+3)/4;        // wave-per-node kernels
  const int NH4  = (N_NODES*4+255)/256;  // thread-per-(node,head) kernels

  // layer 0: cew GAT (A = fp32 input x)
  k_gemm_f32A<<<MT*2,256,0,stream>>>(i_x, cewWt, i_cewB, h0, 128, 128, 2, flag + 1);
  k_diag_nz<<<16,256,0,stream>>>(h0, N_NODES*128, 1562, flag + 2);
  k_rowdot_cew<<<(N_NODES+255)/256,256,0,stream>>>(h0, i_cewA, sbuf);
  k_agg_cew<<<NAGG,256,0,stream>>>(h0, sbuf, i_cew, ro, perm, x1);

  // layer 1: GAT(128 -> 4x64)
  k_gemm_bf16A<<<MT*4,256,0,stream>>>(x1, W1t, nullptr, h1, 128, 256, 4);
  k_rowdot4<<<NH4,256,0,stream>>>(h1, i_aS1, i_aD1, aS, aD);
  k_agg_gat<64,256><<<NAGG,256,0,stream>>>(h1, aS, aD, i_b1, ro, perm, x2);

  // layer 2: GAT(256 -> 4x32)
  k_gemm_bf16A<<<MT*2,256,0,stream>>>(x2, W2t, nullptr, h2, 256, 128, 2);
  k_rowdot2<<<NH4,256,0,stream>>>(h2, i_aS2, i_aD2, aS, aD);
  k_agg_gat<32,128><<<NAGG,256,0,stream>>>(h2, aS, aD, i_b2, ro, perm, x3);
  k_diag_nz<<<16,256,0,stream>>>(x3, N_NODES*128, 1562, flag + 3);

  // layer 3: transformer conv
  k_gemm_bf16A<<<MT*4,256,0,stream>>>(x3, Wqt, i_bq, qb, 128, 256, 4);
  k_gemm_bf16A<<<MT*4,256,0,stream>>>(x3, Wkt, i_bk, kb, 128, 256, 4);
  k_tr_logits<<<(N_EDGES*4+255)/256,256,0,stream>>>(qb, kb, perm, pdst, tlog);
  k_tr_max<<<NH4,256,0,stream>>>(ro, tlog, mbuf);
  k_gemm_bf16A<<<MT*4,256,0,stream>>>(x3, Wvt, i_bv, vb, 128, 256, 4);
  k_gemm_bf16A<<<MT*2,256,0,stream>>>(x3, Wskt, i_bsk, skipb, 128, 128, 2);
  k_trans2<<<NAGG,256,0,stream>>>(vb, skipb, ro, perm, tlog, mbuf, x4);
  k_diag_nz<<<16,256,0,stream>>>(x4, N_NODES*64, 781, flag + 4);

  // final linear (fp32 out), then gated diag override
  k_final<<<(N_NODES*32+255)/256,256,0,stream>>>(x4, i_Wf, i_bf, outf);
  k_diag_end<<<(N_NODES*32+255)/256,256,0,stream>>>(flag, outf);
}

// Round 9
// 823.441 us; speedup vs baseline: 1.5251x; 1.5251x over previous
//
#include <hip/hip_runtime.h>
#include <stdint.h>

#define N_NODES 50000
#define N_EDGES 400000
#define NBLK_SC 196        // ceil(50000/256)
#define MT128   391        // ceil(50000/128) m-tiles

typedef unsigned short u16;
typedef __attribute__((ext_vector_type(8))) short short8;
typedef __attribute__((ext_vector_type(4))) float f32x4;

__device__ __forceinline__ float b2f(u16 u){ unsigned int x=((unsigned int)u)<<16; float f; __builtin_memcpy(&f,&x,4); return f; }
__device__ __forceinline__ u16 f2b(float f){ unsigned int x; __builtin_memcpy(&x,&f,4); x += 0x7fffu + ((x>>16)&1u); return (u16)(x>>16); }

// ---------------- utility ----------------
__global__ void k_zeroi(int* __restrict__ p, int n){
  int i = blockIdx.x*256+threadIdx.x;
  if (i < n) p[i] = 0;
}
__global__ void k_fillf(float* __restrict__ p, int n, float v){
  int i = blockIdx.x*256+threadIdx.x;
  if (i < n) p[i] = v;
}
// fp32 -> bf16 cast of node features
__global__ void k_cvt_x(const float* __restrict__ x, u16* __restrict__ xb, int n){
  int i = blockIdx.x*256+threadIdx.x;
  if (i < n) xb[i] = f2b(x[i]);
}
// Wt[n*K+k] = bf16(W[k*Nc+n]), zero-pad n in [Nc,Npad)
__global__ void k_transpose_b(const float* __restrict__ W, u16* __restrict__ Wt, int K, int Nc, int Npad){
  int i = blockIdx.x*256+threadIdx.x;
  if (i >= Npad*K) return;
  int n = i / K, k = i - n*K;
  Wt[i] = (n < Nc) ? f2b(W[k*Nc + n]) : (u16)0;
}

// ---------------- CSR build ----------------
__global__ void k_count(const int* __restrict__ dst, int* __restrict__ cnt){
  int e = blockIdx.x*256+threadIdx.x;
  if (e < N_EDGES) atomicAdd(&cnt[dst[e]], 1);
}
__global__ void k_scan1(const int* __restrict__ cnt, int* __restrict__ ro, int* __restrict__ bsums){
  __shared__ int sm[256];
  int b = blockIdx.x, t = threadIdx.x, i = b*256+t;
  int v = (i < N_NODES) ? cnt[i] : 0;
  sm[t] = v; __syncthreads();
  for (int off=1; off<256; off<<=1){
    int x = 0; if (t>=off) x = sm[t-off];
    __syncthreads();
    if (t>=off) sm[t] += x;
    __syncthreads();
  }
  if (i < N_NODES) ro[i] = sm[t]-v;
  if (t==255) bsums[b] = sm[255];
}
__global__ void k_scan2(int* __restrict__ bsums, int nb){
  __shared__ int sm[256];
  int t = threadIdx.x;
  int v = (t<nb) ? bsums[t] : 0;
  sm[t]=v; __syncthreads();
  for (int off=1; off<256; off<<=1){
    int x = 0; if (t>=off) x = sm[t-off];
    __syncthreads();
    if (t>=off) sm[t] += x;
    __syncthreads();
  }
  if (t<nb) bsums[t] = sm[t]-v;
}
__global__ void k_scan3(int* __restrict__ ro, const int* __restrict__ bsums){
  int b = blockIdx.x, t = threadIdx.x, i = b*256+t;
  if (i < N_NODES) ro[i] += bsums[b];
  if (i == 0) ro[N_NODES] = N_EDGES;
}
__global__ void k_scatter(const int* __restrict__ src, const int* __restrict__ dst,
                          const int* __restrict__ ro, int* __restrict__ cursor,
                          int* __restrict__ perm){
  int e = blockIdx.x*256+threadIdx.x;
  if (e >= N_EDGES) return;
  int d = dst[e];
  int pos = ro[d] + atomicAdd(&cursor[d], 1);
  perm[pos] = src[e];
}

// ---------------- MFMA GEMM: C[N x Nst] = A[N x K] @ Bt^T + bias ----------------
// A bf16 [N x K] (row-guarded), Bt bf16 [Npad x K] pre-transposed.
// 128x128 tile, 4 waves (2x2 of 64x64), 16x16x32 bf16 MFMA.
// C/D layout: col = lane&15, row = (lane>>4)*4 + r   [m89-verified]
__global__ __launch_bounds__(256)
void k_gemm_mfma(const u16* __restrict__ A, const u16* __restrict__ Bt,
                 const float* __restrict__ bias, u16* __restrict__ C,
                 int K, int Nst, int nTiles)
{
  __shared__ u16 sA[128][40];   // 80B rows, 16B-aligned
  __shared__ u16 sB[128][40];
  int t = threadIdx.x, lane = t & 63, wave = t >> 6;
  int wr = wave >> 1, wc = wave & 1;
  int mTile = blockIdx.x / nTiles, nTile = blockIdx.x - mTile*nTiles;
  int mBase = mTile*128, nBase = nTile*128;
  f32x4 acc[4][4] = {};
  const int row = lane & 15, kq = (lane >> 4) * 8;
  for (int k0 = 0; k0 < K; k0 += 32){
    #pragma unroll
    for (int it = 0; it < 2; ++it){
      int c = it*256 + t;
      int m = c >> 2, ko = (c & 3) * 8;
      int ra = mBase + m;
      uint4 va = {0u,0u,0u,0u};
      if (ra < N_NODES) va = *(const uint4*)(A + (size_t)ra*K + k0 + ko);
      *(uint4*)&sA[m][ko] = va;
      *(uint4*)&sB[m][ko] = *(const uint4*)(Bt + (size_t)(nBase+m)*K + k0 + ko);
    }
    __syncthreads();
    short8 af[4], bfr[4];
    #pragma unroll
    for (int i=0;i<4;i++) af[i]  = *(const short8*)&sA[wr*64 + i*16 + row][kq];
    #pragma unroll
    for (int i=0;i<4;i++) bfr[i] = *(const short8*)&sB[wc*64 + i*16 + row][kq];
    #pragma unroll
    for (int i=0;i<4;i++)
      #pragma unroll
      for (int j=0;j<4;j++)
        acc[i][j] = __builtin_amdgcn_mfma_f32_16x16x32_bf16(af[i], bfr[j], acc[i][j], 0,0,0);
    __syncthreads();
  }
  #pragma unroll
  for (int i=0;i<4;i++)
    #pragma unroll
    for (int j=0;j<4;j++)
      #pragma unroll
      for (int r=0;r<4;r++){
        int mm = mBase + wr*64 + i*16 + (lane>>4)*4 + r;
        if (mm >= N_NODES) continue;
        int nn = nBase + wc*64 + j*16 + (lane&15);
        float v = acc[i][j][r];
        if (bias) v += bias[nn];
        C[(size_t)mm*Nst + nn] = f2b(v);
      }
}

// ---------------- row-dots (thread-serial) ----------------
__global__ __launch_bounds__(256)
void k_rowdot_cew(const u16* __restrict__ hb, const float* __restrict__ att, float* __restrict__ s){
  int n = blockIdx.x*256+threadIdx.x;
  if (n >= N_NODES) return;
  const u16* hp = hb + (size_t)n*128;
  float acc = 0.f;
  #pragma unroll 8
  for (int c=0;c<128;++c) acc += b2f(hp[c])*att[c];
  s[n] = acc;
}
__global__ __launch_bounds__(256)
void k_rowdot4(const u16* __restrict__ hb, const float* __restrict__ attS, const float* __restrict__ attD,
               float* __restrict__ aS, float* __restrict__ aD){
  int t = blockIdx.x*256+threadIdx.x;
  if (t >= N_NODES*4) return;
  int n = t>>2, h = t&3;
  const u16* hp = hb + (size_t)n*256 + h*64;
  const float* as = attS + h*64;
  const float* ad = attD + h*64;
  float ps=0.f, pd=0.f;
  #pragma unroll 8
  for (int c=0;c<64;++c){ float v=b2f(hp[c]); ps += v*as[c]; pd += v*ad[c]; }
  aS[t]=ps; aD[t]=pd;
}
__global__ __launch_bounds__(256)
void k_rowdot2(const u16* __restrict__ hb, const float* __restrict__ attS, const float* __restrict__ attD,
               float* __restrict__ aS, float* __restrict__ aD){
  int t = blockIdx.x*256+threadIdx.x;
  if (t >= N_NODES*4) return;
  int n = t>>2, h = t&3;
  const u16* hp = hb + (size_t)n*128 + h*32;
  const float* as = attS + h*32;
  const float* ad = attD + h*32;
  float ps=0.f, pd=0.f;
  #pragma unroll 8
  for (int c=0;c<32;++c){ float v=b2f(hp[c]); ps += v*as[c]; pd += v*ad[c]; }
  aS[t]=ps; aD[t]=pd;
}

// ---------------- aggregation (wave per node; serial redundant max) ----------------
__global__ __launch_bounds__(256)
void k_agg_cew(const u16* __restrict__ h0, const float* __restrict__ s, const float* __restrict__ cewf,
               const int* __restrict__ ro, const int* __restrict__ perm, u16* __restrict__ x1)
{
  int wave = threadIdx.x>>6, lane = threadIdx.x&63;
  int node = blockIdx.x*4 + wave;
  if (node >= N_NODES) return;
  float sd = s[node], cd = cewf[node];
  int beg = ro[node], end = ro[node+1];
  float m = -INFINITY;
  for (int j=beg; j<end; ++j){
    int u = perm[j];
    float a = s[u] + sd; a = a>=0.f ? a : 0.01f*a;
    a *= (cewf[u] + cd);
    m = fmaxf(m, a);
  }
  float den = 0.f, a0 = 0.f, a1 = 0.f;
  int f = 2*lane;
  for (int j=beg; j<end; ++j){
    int u = perm[j];
    float a = s[u] + sd; a = a>=0.f ? a : 0.01f*a;
    a *= (cewf[u] + cd);
    float w = __expf(a - m);
    den += w;
    unsigned int pv = *(const unsigned int*)(h0 + (size_t)u*128 + f);
    a0 += w * b2f((u16)(pv & 0xffffu));
    a1 += w * b2f((u16)(pv >> 16));
  }
  float inv = 1.f/(den + 1e-16f);
  float o0 = a0*inv; o0 = o0>0.f?o0:0.f;
  float o1 = a1*inv; o1 = o1>0.f?o1:0.f;
  *(unsigned int*)(x1 + (size_t)node*128 + f) = (unsigned int)f2b(o0) | ((unsigned int)f2b(o1)<<16);
}

template<int C, int F>
__global__ __launch_bounds__(256)
void k_agg_gat(const u16* __restrict__ hb, const float* __restrict__ aS, const float* __restrict__ aD,
               const float* __restrict__ bias, const int* __restrict__ ro, const int* __restrict__ perm,
               u16* __restrict__ out)
{
  int wave = threadIdx.x>>6, lane = threadIdx.x&63;
  int node = blockIdx.x*4 + wave;
  if (node >= N_NODES) return;
  auto lk = [](float x){ return x>=0.f ? x : 0.2f*x; };
  float ad0=aD[node*4+0], ad1=aD[node*4+1], ad2=aD[node*4+2], ad3=aD[node*4+3];
  float sl0=lk(aS[node*4+0]+ad0), sl1=lk(aS[node*4+1]+ad1),
        sl2=lk(aS[node*4+2]+ad2), sl3=lk(aS[node*4+3]+ad3);   // self-loop logits
  int beg = ro[node], end = ro[node+1];
  float m0=sl0, m1=sl1, m2=sl2, m3=sl3;
  for (int j=beg; j<end; ++j){
    int u = perm[j];
    m0 = fmaxf(m0, lk(aS[u*4+0]+ad0));
    m1 = fmaxf(m1, lk(aS[u*4+1]+ad1));
    m2 = fmaxf(m2, lk(aS[u*4+2]+ad2));
    m3 = fmaxf(m3, lk(aS[u*4+3]+ad3));
  }
  constexpr int CH = F/128;
  float ax[CH], ay[CH];
  int hd[CH];
  #pragma unroll
  for (int c=0;c<CH;++c){ ax[c]=0.f; ay[c]=0.f; hd[c] = (c*128 + 2*lane)/C; }
  float d0=0.f,d1=0.f,d2=0.f,d3=0.f;
  {
    float w0=__expf(sl0-m0), w1=__expf(sl1-m1), w2=__expf(sl2-m2), w3=__expf(sl3-m3);
    d0+=w0; d1+=w1; d2+=w2; d3+=w3;
    #pragma unroll
    for (int c=0;c<CH;++c){
      int f = c*128 + 2*lane;
      float ws = hd[c]==0?w0 : hd[c]==1?w1 : hd[c]==2?w2 : w3;
      unsigned int pv = *(const unsigned int*)(hb + (size_t)node*F + f);
      ax[c] += ws * b2f((u16)(pv & 0xffffu));
      ay[c] += ws * b2f((u16)(pv >> 16));
    }
  }
  for (int j=beg; j<end; ++j){
    int u = perm[j];
    float e0=__expf(lk(aS[u*4+0]+ad0)-m0), e1=__expf(lk(aS[u*4+1]+ad1)-m1),
          e2=__expf(lk(aS[u*4+2]+ad2)-m2), e3=__expf(lk(aS[u*4+3]+ad3)-m3);
    d0+=e0; d1+=e1; d2+=e2; d3+=e3;
    #pragma unroll
    for (int c=0;c<CH;++c){
      int f = c*128 + 2*lane;
      float we = hd[c]==0?e0 : hd[c]==1?e1 : hd[c]==2?e2 : e3;
      unsigned int pv = *(const unsigned int*)(hb + (size_t)u*F + f);
      ax[c] += we * b2f((u16)(pv & 0xffffu));
      ay[c] += we * b2f((u16)(pv >> 16));
    }
  }
  #pragma unroll
  for (int c=0;c<CH;++c){
    int f = c*128 + 2*lane;
    float dd = (hd[c]==0?d0 : hd[c]==1?d1 : hd[c]==2?d2 : d3) + 1e-16f;
    float ox = ax[c]/dd + bias[f];   ox = ox>0.f?ox:0.f;
    float oy = ay[c]/dd + bias[f+1]; oy = oy>0.f?oy:0.f;
    *(unsigned int*)(out + (size_t)node*F + f) = (unsigned int)f2b(ox) | ((unsigned int)f2b(oy)<<16);
  }
}

// ---------------- transformer conv ----------------
// fused logits + max: one wave per dst node; q in registers, coalesced k-row reads,
// 64-lane shuffle reduction per head.
__global__ __launch_bounds__(256)
void k_tr1(const u16* __restrict__ qb, const u16* __restrict__ kb,
           const int* __restrict__ ro, const int* __restrict__ perm,
           float* __restrict__ tlog, float* __restrict__ mbuf)
{
  int wave = threadIdx.x>>6, lane = threadIdx.x&63;
  int node = blockIdx.x*4 + wave;
  if (node >= N_NODES) return;
  const u16* qp = qb + (size_t)node*256;
  float q0=b2f(qp[lane]), q1=b2f(qp[64+lane]), q2=b2f(qp[128+lane]), q3=b2f(qp[192+lane]);
  float m0=-INFINITY,m1=-INFINITY,m2=-INFINITY,m3=-INFINITY;
  int beg = ro[node], end = ro[node+1];
  for (int j=beg; j<end; ++j){
    int u = perm[j];
    const u16* kp = kb + (size_t)u*256;
    float p0=q0*b2f(kp[lane]),     p1=q1*b2f(kp[64+lane]),
          p2=q2*b2f(kp[128+lane]), p3=q3*b2f(kp[192+lane]);
    #pragma unroll
    for (int o=32;o;o>>=1){
      p0 += __shfl_xor(p0,o); p1 += __shfl_xor(p1,o);
      p2 += __shfl_xor(p2,o); p3 += __shfl_xor(p3,o);
    }
    p0*=0.125f; p1*=0.125f; p2*=0.125f; p3*=0.125f;
    m0=fmaxf(m0,p0); m1=fmaxf(m1,p1); m2=fmaxf(m2,p2); m3=fmaxf(m3,p3);
    if (lane==0){ tlog[j*4+0]=p0; tlog[j*4+1]=p1; tlog[j*4+2]=p2; tlog[j*4+3]=p3; }
  }
  if (lane==0){ mbuf[node*4+0]=m0; mbuf[node*4+1]=m1; mbuf[node*4+2]=m2; mbuf[node*4+3]=m3; }
}

__global__ __launch_bounds__(256)
void k_trans2(const u16* __restrict__ vb, const u16* __restrict__ skipb,
              const float* __restrict__ bsk,
              const int* __restrict__ ro, const int* __restrict__ perm,
              const float* __restrict__ tlog, const float* __restrict__ mbuf, u16* __restrict__ x4)
{
  int wave = threadIdx.x>>6, lane = threadIdx.x&63;
  int node = blockIdx.x*4 + wave;
  if (node >= N_NODES) return;
  float m0=mbuf[node*4+0], m1=mbuf[node*4+1], m2=mbuf[node*4+2], m3=mbuf[node*4+3];
  float d0=0.f,d1=0.f,d2=0.f,d3=0.f, a0=0.f,a1=0.f,a2=0.f,a3=0.f;
  int beg = ro[node], end = ro[node+1];
  for (int j=beg; j<end; ++j){
    int u = perm[j];
    const size_t vbase = (size_t)u*256;
    float e0=__expf(tlog[j*4+0]-m0), e1=__expf(tlog[j*4+1]-m1),
          e2=__expf(tlog[j*4+2]-m2), e3=__expf(tlog[j*4+3]-m3);
    d0+=e0; d1+=e1; d2+=e2; d3+=e3;
    a0 += e0*b2f(vb[vbase+lane]);     a1 += e1*b2f(vb[vbase+64+lane]);
    a2 += e2*b2f(vb[vbase+128+lane]); a3 += e3*b2f(vb[vbase+192+lane]);
  }
  float o = 0.25f*( a0/(d0+1e-16f) + a1/(d1+1e-16f) + a2/(d2+1e-16f) + a3/(d3+1e-16f) );
  o += b2f(skipb[(size_t)node*128 + lane]) + bsk[lane];   // skip linear + its bias
  o = o>0.f ? o : 0.f;
  x4[(size_t)node*64 + lane] = f2b(o);
}

// ---------------- final linear 64 -> 32, fp32 out ----------------
__global__ __launch_bounds__(256)
void k_final(const u16* __restrict__ x4, const float* __restrict__ Wf, const float* __restrict__ bf,
             float* __restrict__ out)
{
  int i = blockIdx.x*256+threadIdx.x;
  if (i >= N_NODES*32) return;
  int n = i>>5, c = i&31;
  const u16* xr = x4 + (size_t)n*64;
  float acc = 0.f;
  #pragma unroll
  for (int k=0;k<64;++k) acc += b2f(xr[k]) * Wf[k*32+c];
  acc += bf[c];
  out[i] = acc;
}

// ---------------- host ----------------
extern "C" void kernel_launch(void* const* d_in, const int* in_sizes, int n_in,
                              void* d_out, int out_size, void* d_ws, size_t ws_size,
                              hipStream_t stream)
{
  const float* i_x    = (const float*)d_in[0];
  const int*   i_ei   = (const int*)d_in[1];
  const float* i_cew  = (const float*)d_in[2];
  const float* i_cewW = (const float*)d_in[3];
  const float* i_cewB = (const float*)d_in[4];
  const float* i_cewA = (const float*)d_in[5];
  const float* i_W1   = (const float*)d_in[6];
  const float* i_aS1  = (const float*)d_in[7];
  const float* i_aD1  = (const float*)d_in[8];
  const float* i_b1   = (const float*)d_in[9];
  const float* i_W2   = (const float*)d_in[10];
  const float* i_aS2  = (const float*)d_in[11];
  const float* i_aD2  = (const float*)d_in[12];
  const float* i_b2   = (const float*)d_in[13];
  const float* i_Wq   = (const float*)d_in[14];
  const float* i_bq   = (const float*)d_in[15];
  const float* i_Wk   = (const float*)d_in[16];
  const float* i_bk   = (const float*)d_in[17];
  const float* i_Wv   = (const float*)d_in[18];
  const float* i_bv   = (const float*)d_in[19];
  const float* i_Wsk  = (const float*)d_in[20];
  const float* i_bsk  = (const float*)d_in[21];
  const float* i_Wf   = (const float*)d_in[22];
  const float* i_bf   = (const float*)d_in[23];
  (void)in_sizes; (void)n_in; (void)out_size;

  char* w = (char*)d_ws;
  size_t off = 0;
  auto A = [&](size_t bytes)->char*{ char* p = w + off; off = (off + bytes + 255) & ~(size_t)255; return p; };

  int*   bsums  = (int*)A(1024);
  float* sbuf   = (float*)A((size_t)N_NODES*4);
  float* aS     = (float*)A((size_t)N_NODES*16);
  float* aD     = (float*)A((size_t)N_NODES*16);
  float* mbuf   = (float*)A((size_t)N_NODES*16);
  int*   cnt    = (int*)A((size_t)N_NODES*4);
  int*   ro     = (int*)A((size_t)(N_NODES+1)*4);
  int*   cursor = (int*)A((size_t)N_NODES*4);
  int*   perm   = (int*)A((size_t)N_EDGES*4);
  float* tlog   = (float*)A((size_t)N_EDGES*16);
  u16*   cewWt  = (u16*)A(128*128*2);
  u16*   W1t    = (u16*)A(256*128*2);
  u16*   W2t    = (u16*)A(128*256*2);
  u16*   Wqt    = (u16*)A(256*128*2);
  u16*   Wkt    = (u16*)A(256*128*2);
  u16*   Wvt    = (u16*)A(256*128*2);
  u16*   Wskt   = (u16*)A(128*128*2);
  u16*   xb     = (u16*)A((size_t)N_NODES*128*2);
  u16* S1 = (u16*)A((size_t)N_NODES*128*2);   // h0 -> h2 -> skipb
  u16* S2 = (u16*)A((size_t)N_NODES*128*2);   // x1 -> x3
  u16* G1 = (u16*)A((size_t)N_NODES*256*2);   // h1 -> qb -> vb
  u16* G2 = (u16*)A((size_t)N_NODES*256*2);   // x2 -> kb -> x4
  size_t need = off;

  float* outf = (float*)d_out;
  if (ws_size < need){
    k_fillf<<<(N_NODES*32+255)/256,256,0,stream>>>(outf, N_NODES*32,
        8192.f + 32.f * (float)((ws_size >> 20) > 255 ? 255 : (ws_size >> 20)));
    return;
  }

  u16* h0 = S1;  u16* x1 = S2;
  u16* h1 = G1;  u16* x2 = G2;
  u16* h2 = S1;  u16* x3 = S2;
  u16* qb = G1;  u16* kb = G2;
  u16* vb = G1;  u16* skipb = S1;  u16* x4 = G2;

  k_zeroi<<<(N_NODES+255)/256,256,0,stream>>>(cnt, N_NODES);
  k_zeroi<<<(N_NODES+255)/256,256,0,stream>>>(cursor, N_NODES);

  // prep: x -> bf16, weights -> transposed bf16
  k_cvt_x<<<(N_NODES*128+255)/256,256,0,stream>>>(i_x, xb, N_NODES*128);
  k_transpose_b<<<(128*128+255)/256,256,0,stream>>>(i_cewW, cewWt, 128, 128, 128);
  k_transpose_b<<<(256*128+255)/256,256,0,stream>>>(i_W1,   W1t,  128, 256, 256);
  k_transpose_b<<<(128*256+255)/256,256,0,stream>>>(i_W2,   W2t,  256, 128, 128);
  k_transpose_b<<<(256*128+255)/256,256,0,stream>>>(i_Wq,   Wqt,  128, 256, 256);
  k_transpose_b<<<(256*128+255)/256,256,0,stream>>>(i_Wk,   Wkt,  128, 256, 256);
  k_transpose_b<<<(256*128+255)/256,256,0,stream>>>(i_Wv,   Wvt,  128, 256, 256);
  k_transpose_b<<<(128*128+255)/256,256,0,stream>>>(i_Wsk,  Wskt, 128, 64, 128);

  // CSR by destination
  k_count<<<(N_EDGES+255)/256,256,0,stream>>>(i_ei + N_EDGES, cnt);
  k_scan1<<<NBLK_SC,256,0,stream>>>(cnt, ro, bsums);
  k_scan2<<<1,256,0,stream>>>(bsums, NBLK_SC);
  k_scan3<<<NBLK_SC,256,0,stream>>>(ro, bsums);
  k_scatter<<<(N_EDGES+255)/256,256,0,stream>>>(i_ei, i_ei + N_EDGES, ro, cursor, perm);

  const int NAGG = (N_NODES+3)/4;
  const int NH4  = (N_NODES*4+255)/256;

  // layer 0: cew GAT
  k_gemm_mfma<<<MT128*1,256,0,stream>>>(xb, cewWt, i_cewB, h0, 128, 128, 1);
  k_rowdot_cew<<<(N_NODES+255)/256,256,0,stream>>>(h0, i_cewA, sbuf);
  k_agg_cew<<<NAGG,256,0,stream>>>(h0, sbuf, i_cew, ro, perm, x1);

  // layer 1: GAT(128 -> 4x64)
  k_gemm_mfma<<<MT128*2,256,0,stream>>>(x1, W1t, nullptr, h1, 128, 256, 2);
  k_rowdot4<<<NH4,256,0,stream>>>(h1, i_aS1, i_aD1, aS, aD);
  k_agg_gat<64,256><<<NAGG,256,0,stream>>>(h1, aS, aD, i_b1, ro, perm, x2);

  // layer 2: GAT(256 -> 4x32)
  k_gemm_mfma<<<MT128*1,256,0,stream>>>(x2, W2t, nullptr, h2, 256, 128, 1);
  k_rowdot2<<<NH4,256,0,stream>>>(h2, i_aS2, i_aD2, aS, aD);
  k_agg_gat<32,128><<<NAGG,256,0,stream>>>(h2, aS, aD, i_b2, ro, perm, x3);

  // layer 3: transformer conv
  k_gemm_mfma<<<MT128*2,256,0,stream>>>(x3, Wqt, i_bq, qb, 128, 256, 2);
  k_gemm_mfma<<<MT128*2,256,0,stream>>>(x3, Wkt, i_bk, kb, 128, 256, 2);
  k_tr1<<<NAGG,256,0,stream>>>(qb, kb, ro, perm, tlog, mbuf);
  k_gemm_mfma<<<MT128*2,256,0,stream>>>(x3, Wvt, i_bv, vb, 128, 256, 2);
  k_gemm_mfma<<<MT128*1,256,0,stream>>>(x3, Wskt, nullptr, skipb, 128, 128, 1);
  k_trans2<<<NAGG,256,0,stream>>>(vb, skipb, i_bsk, ro, perm, tlog, mbuf, x4);

  // final linear (fp32 out)
  k_final<<<(N_NODES*32+255)/256,256,0,stream>>>(x4, i_Wf, i_bf, outf);
}

// Round 10
// 687.965 us; speedup vs baseline: 1.8254x; 1.1969x over previous
//
#include <hip/hip_runtime.h>
#include <stdint.h>

#define N_NODES 50000
#define N_EDGES 400000
#define NBLK_SC 196        // ceil(50000/256)
#define MT128   391        // ceil(50000/128) m-tiles

typedef unsigned short u16;
typedef __attribute__((ext_vector_type(8))) short short8;
typedef __attribute__((ext_vector_type(4))) float f32x4;

__device__ __forceinline__ float b2f(u16 u){ unsigned int x=((unsigned int)u)<<16; float f; __builtin_memcpy(&f,&x,4); return f; }
__device__ __forceinline__ u16 f2b(float f){ unsigned int x; __builtin_memcpy(&x,&f,4); x += 0x7fffu + ((x>>16)&1u); return (u16)(x>>16); }

// ---------------- utility ----------------
__global__ void k_zeroi(int* __restrict__ p, int n){
  int i = blockIdx.x*256+threadIdx.x;
  if (i < n) p[i] = 0;
}
__global__ void k_fillf(float* __restrict__ p, int n, float v){
  int i = blockIdx.x*256+threadIdx.x;
  if (i < n) p[i] = v;
}
__global__ void k_cvt_x(const float* __restrict__ x, u16* __restrict__ xb, int n){
  int i = blockIdx.x*256+threadIdx.x;
  if (i < n) xb[i] = f2b(x[i]);
}
// Wt[n*K+k] = bf16(W[k*Nc+n]), zero-pad n in [Nc,Npad)
__global__ void k_transpose_b(const float* __restrict__ W, u16* __restrict__ Wt, int K, int Nc, int Npad){
  int i = blockIdx.x*256+threadIdx.x;
  if (i >= Npad*K) return;
  int n = i / K, k = i - n*K;
  Wt[i] = (n < Nc) ? f2b(W[k*Nc + n]) : (u16)0;
}
// concatenated transpose for q|k|v|skip, Wt[896*128]
__global__ void k_transpose_cat(const float* __restrict__ Wq, const float* __restrict__ Wk,
                                const float* __restrict__ Wv, const float* __restrict__ Wsk,
                                u16* __restrict__ Wt){
  int i = blockIdx.x*256+threadIdx.x;
  if (i >= 896*128) return;
  int n = i >> 7, k = i & 127;
  float v = 0.f;
  if      (n < 256) v = Wq[k*256 + n];
  else if (n < 512) v = Wk[k*256 + (n-256)];
  else if (n < 768) v = Wv[k*256 + (n-512)];
  else if (n < 832) v = Wsk[k*64 + (n-768)];
  Wt[i] = f2b(v);
}

// ---------------- CSR build ----------------
__global__ void k_count(const int* __restrict__ dst, int* __restrict__ cnt){
  int e = blockIdx.x*256+threadIdx.x;
  if (e < N_EDGES) atomicAdd(&cnt[dst[e]], 1);
}
__global__ void k_scan1(const int* __restrict__ cnt, int* __restrict__ ro, int* __restrict__ bsums){
  __shared__ int sm[256];
  int b = blockIdx.x, t = threadIdx.x, i = b*256+t;
  int v = (i < N_NODES) ? cnt[i] : 0;
  sm[t] = v; __syncthreads();
  for (int off=1; off<256; off<<=1){
    int x = 0; if (t>=off) x = sm[t-off];
    __syncthreads();
    if (t>=off) sm[t] += x;
    __syncthreads();
  }
  if (i < N_NODES) ro[i] = sm[t]-v;
  if (t==255) bsums[b] = sm[255];
}
__global__ void k_scan2(int* __restrict__ bsums, int nb){
  __shared__ int sm[256];
  int t = threadIdx.x;
  int v = (t<nb) ? bsums[t] : 0;
  sm[t]=v; __syncthreads();
  for (int off=1; off<256; off<<=1){
    int x = 0; if (t>=off) x = sm[t-off];
    __syncthreads();
    if (t>=off) sm[t] += x;
    __syncthreads();
  }
  if (t<nb) bsums[t] = sm[t]-v;
}
__global__ void k_scan3(int* __restrict__ ro, const int* __restrict__ bsums){
  int b = blockIdx.x, t = threadIdx.x, i = b*256+t;
  if (i < N_NODES) ro[i] += bsums[b];
  if (i == 0) ro[N_NODES] = N_EDGES;
}
__global__ void k_scatter(const int* __restrict__ src, const int* __restrict__ dst,
                          const int* __restrict__ ro, int* __restrict__ cursor,
                          int* __restrict__ perm){
  int e = blockIdx.x*256+threadIdx.x;
  if (e >= N_EDGES) return;
  int d = dst[e];
  int pos = ro[d] + atomicAdd(&cursor[d], 1);
  perm[pos] = src[e];
}

// ---------------- MFMA GEMM: C[N x Nst] = A[N x K] @ Bt^T + bias ----------------
__global__ __launch_bounds__(256)
void k_gemm_mfma(const u16* __restrict__ A, const u16* __restrict__ Bt,
                 const float* __restrict__ bias, u16* __restrict__ C,
                 int K, int Nst, int nTiles)
{
  __shared__ u16 sA[128][40];
  __shared__ u16 sB[128][40];
  int t = threadIdx.x, lane = t & 63, wave = t >> 6;
  int wr = wave >> 1, wc = wave & 1;
  int mTile = blockIdx.x / nTiles, nTile = blockIdx.x - mTile*nTiles;
  int mBase = mTile*128, nBase = nTile*128;
  f32x4 acc[4][4] = {};
  const int row = lane & 15, kq = (lane >> 4) * 8;
  for (int k0 = 0; k0 < K; k0 += 32){
    #pragma unroll
    for (int it = 0; it < 2; ++it){
      int c = it*256 + t;
      int m = c >> 2, ko = (c & 3) * 8;
      int ra = mBase + m;
      uint4 va = {0u,0u,0u,0u};
      if (ra < N_NODES) va = *(const uint4*)(A + (size_t)ra*K + k0 + ko);
      *(uint4*)&sA[m][ko] = va;
      *(uint4*)&sB[m][ko] = *(const uint4*)(Bt + (size_t)(nBase+m)*K + k0 + ko);
    }
    __syncthreads();
    short8 af[4], bfr[4];
    #pragma unroll
    for (int i=0;i<4;i++) af[i]  = *(const short8*)&sA[wr*64 + i*16 + row][kq];
    #pragma unroll
    for (int i=0;i<4;i++) bfr[i] = *(const short8*)&sB[wc*64 + i*16 + row][kq];
    #pragma unroll
    for (int i=0;i<4;i++)
      #pragma unroll
      for (int j=0;j<4;j++)
        acc[i][j] = __builtin_amdgcn_mfma_f32_16x16x32_bf16(af[i], bfr[j], acc[i][j], 0,0,0);
    __syncthreads();
  }
  #pragma unroll
  for (int i=0;i<4;i++)
    #pragma unroll
    for (int j=0;j<4;j++)
      #pragma unroll
      for (int r=0;r<4;r++){
        int mm = mBase + wr*64 + i*16 + (lane>>4)*4 + r;
        if (mm >= N_NODES) continue;
        int nn = nBase + wc*64 + j*16 + (lane&15);
        float v = acc[i][j][r];
        if (bias) v += bias[nn];
        C[(size_t)mm*Nst + nn] = f2b(v);
      }
}

// fused q|k|v|skip GEMM: K=128, 896 output cols routed to 4 buffers
__global__ __launch_bounds__(256)
void k_gemm_qkvs(const u16* __restrict__ A, const u16* __restrict__ Bt,
                 const float* __restrict__ bq, const float* __restrict__ bk,
                 const float* __restrict__ bv,
                 u16* __restrict__ qb, u16* __restrict__ kb, u16* __restrict__ vb,
                 u16* __restrict__ skipb)
{
  __shared__ u16 sA[128][40];
  __shared__ u16 sB[128][40];
  int t = threadIdx.x, lane = t & 63, wave = t >> 6;
  int wr = wave >> 1, wc = wave & 1;
  int mTile = blockIdx.x / 7, nTile = blockIdx.x - mTile*7;
  int mBase = mTile*128, nBase = nTile*128;
  f32x4 acc[4][4] = {};
  const int row = lane & 15, kq = (lane >> 4) * 8;
  const int K = 128;
  for (int k0 = 0; k0 < K; k0 += 32){
    #pragma unroll
    for (int it = 0; it < 2; ++it){
      int c = it*256 + t;
      int m = c >> 2, ko = (c & 3) * 8;
      int ra = mBase + m;
      uint4 va = {0u,0u,0u,0u};
      if (ra < N_NODES) va = *(const uint4*)(A + (size_t)ra*K + k0 + ko);
      *(uint4*)&sA[m][ko] = va;
      *(uint4*)&sB[m][ko] = *(const uint4*)(Bt + (size_t)(nBase+m)*K + k0 + ko);
    }
    __syncthreads();
    short8 af[4], bfr[4];
    #pragma unroll
    for (int i=0;i<4;i++) af[i]  = *(const short8*)&sA[wr*64 + i*16 + row][kq];
    #pragma unroll
    for (int i=0;i<4;i++) bfr[i] = *(const short8*)&sB[wc*64 + i*16 + row][kq];
    #pragma unroll
    for (int i=0;i<4;i++)
      #pragma unroll
      for (int j=0;j<4;j++)
        acc[i][j] = __builtin_amdgcn_mfma_f32_16x16x32_bf16(af[i], bfr[j], acc[i][j], 0,0,0);
    __syncthreads();
  }
  #pragma unroll
  for (int j=0;j<4;j++){
    int nn = nBase + wc*64 + j*16 + (lane&15);
    u16* dst; int stride, col; float bias;
    if      (nn < 256){ dst=qb;    stride=256; col=nn;     bias=bq[nn];     }
    else if (nn < 512){ dst=kb;    stride=256; col=nn-256; bias=bk[nn-256]; }
    else if (nn < 768){ dst=vb;    stride=256; col=nn-512; bias=bv[nn-512]; }
    else if (nn < 832){ dst=skipb; stride=64;  col=nn-768; bias=0.f;        }
    else continue;
    #pragma unroll
    for (int i=0;i<4;i++)
      #pragma unroll
      for (int r=0;r<4;r++){
        int mm = mBase + wr*64 + i*16 + (lane>>4)*4 + r;
        if (mm >= N_NODES) continue;
        dst[(size_t)mm*stride + col] = f2b(acc[i][j][r] + bias);
      }
  }
}

// ---------------- row-dots (thread-serial) ----------------
__global__ __launch_bounds__(256)
void k_rowdot_cew(const u16* __restrict__ hb, const float* __restrict__ att, float* __restrict__ s){
  int n = blockIdx.x*256+threadIdx.x;
  if (n >= N_NODES) return;
  const u16* hp = hb + (size_t)n*128;
  float acc = 0.f;
  #pragma unroll 8
  for (int c=0;c<128;++c) acc += b2f(hp[c])*att[c];
  s[n] = acc;
}
__global__ __launch_bounds__(256)
void k_rowdot4(const u16* __restrict__ hb, const float* __restrict__ attS, const float* __restrict__ attD,
               float* __restrict__ aS, float* __restrict__ aD){
  int t = blockIdx.x*256+threadIdx.x;
  if (t >= N_NODES*4) return;
  int n = t>>2, h = t&3;
  const u16* hp = hb + (size_t)n*256 + h*64;
  const float* as = attS + h*64;
  const float* ad = attD + h*64;
  float ps=0.f, pd=0.f;
  #pragma unroll 8
  for (int c=0;c<64;++c){ float v=b2f(hp[c]); ps += v*as[c]; pd += v*ad[c]; }
  aS[t]=ps; aD[t]=pd;
}
__global__ __launch_bounds__(256)
void k_rowdot2(const u16* __restrict__ hb, const float* __restrict__ attS, const float* __restrict__ attD,
               float* __restrict__ aS, float* __restrict__ aD){
  int t = blockIdx.x*256+threadIdx.x;
  if (t >= N_NODES*4) return;
  int n = t>>2, h = t&3;
  const u16* hp = hb + (size_t)n*128 + h*32;
  const float* as = attS + h*32;
  const float* ad = attD + h*32;
  float ps=0.f, pd=0.f;
  #pragma unroll 8
  for (int c=0;c<32;++c){ float v=b2f(hp[c]); ps += v*as[c]; pd += v*ad[c]; }
  aS[t]=ps; aD[t]=pd;
}

// ---------------- layer-0 aggregation (single softmax) ----------------
__global__ __launch_bounds__(256)
void k_agg_cew(const u16* __restrict__ h0, const float* __restrict__ s, const float* __restrict__ cewf,
               const int* __restrict__ ro, const int* __restrict__ perm, u16* __restrict__ x1)
{
  int wave = threadIdx.x>>6, lane = threadIdx.x&63;
  int node = blockIdx.x*4 + wave;
  if (node >= N_NODES) return;
  float sd = s[node], cd = cewf[node];
  int beg = ro[node], end = ro[node+1];
  float m = -INFINITY;
  for (int j=beg; j<end; ++j){
    int u = perm[j];
    float a = s[u] + sd; a = a>=0.f ? a : 0.01f*a;
    a *= (cewf[u] + cd);
    m = fmaxf(m, a);
  }
  float den = 0.f, a0 = 0.f, a1 = 0.f;
  int f = 2*lane;
  for (int j=beg; j<end; ++j){
    int u = perm[j];
    float a = s[u] + sd; a = a>=0.f ? a : 0.01f*a;
    a *= (cewf[u] + cd);
    float w = __expf(a - m);
    den += w;
    unsigned int pv = *(const unsigned int*)(h0 + (size_t)u*128 + f);
    a0 += w * b2f((u16)(pv & 0xffffu));
    a1 += w * b2f((u16)(pv >> 16));
  }
  float inv = 1.f/(den + 1e-16f);
  float o0 = a0*inv; o0 = o0>0.f?o0:0.f;
  float o1 = a1*inv; o1 = o1>0.f?o1:0.f;
  *(unsigned int*)(x1 + (size_t)node*128 + f) = (unsigned int)f2b(o0) | ((unsigned int)f2b(o1)<<16);
}

// ---------------- GAT aggregation, head-parallel: 16 lanes per head ----------------
// layer 1: F=256, C=64 -> lane h*16+l owns out channels h*64 + 4l..4l+3
__global__ __launch_bounds__(256)
void k_agg_gat1(const u16* __restrict__ hb, const float* __restrict__ aS, const float* __restrict__ aD,
                const float* __restrict__ bias, const int* __restrict__ ro, const int* __restrict__ perm,
                u16* __restrict__ out)
{
  int wave = threadIdx.x>>6, lane = threadIdx.x&63;
  int node = blockIdx.x*4 + wave;
  if (node >= N_NODES) return;
  int h = lane >> 4, l = lane & 15;
  auto lk = [](float x){ return x>=0.f ? x : 0.2f*x; };
  float ad = aD[node*4+h];
  float sl = lk(aS[node*4+h] + ad);
  int beg = ro[node], end = ro[node+1];
  float m = sl;
  for (int j=beg; j<end; ++j)
    m = fmaxf(m, lk(aS[perm[j]*4+h] + ad));
  int fo = h*64 + l*4;
  float d, c0,c1,c2,c3;
  {
    float wv = __expf(sl - m);
    d = wv;
    ushort4 pv = *(const ushort4*)(hb + (size_t)node*256 + fo);
    c0 = wv*b2f(pv.x); c1 = wv*b2f(pv.y); c2 = wv*b2f(pv.z); c3 = wv*b2f(pv.w);
  }
  for (int j=beg; j<end; ++j){
    int u = perm[j];
    float e = __expf(lk(aS[u*4+h] + ad) - m);
    d += e;
    ushort4 pv = *(const ushort4*)(hb + (size_t)u*256 + fo);
    c0 += e*b2f(pv.x); c1 += e*b2f(pv.y); c2 += e*b2f(pv.z); c3 += e*b2f(pv.w);
  }
  float inv = 1.f/(d + 1e-16f);
  float o0 = c0*inv + bias[fo+0]; o0 = o0>0.f?o0:0.f;
  float o1 = c1*inv + bias[fo+1]; o1 = o1>0.f?o1:0.f;
  float o2 = c2*inv + bias[fo+2]; o2 = o2>0.f?o2:0.f;
  float o3 = c3*inv + bias[fo+3]; o3 = o3>0.f?o3:0.f;
  ushort4 ov = { f2b(o0), f2b(o1), f2b(o2), f2b(o3) };
  *(ushort4*)(out + (size_t)node*256 + fo) = ov;
}

// layer 2: F=128, C=32 -> lane h*16+l owns out channels h*32 + 2l..2l+1
__global__ __launch_bounds__(256)
void k_agg_gat2(const u16* __restrict__ hb, const float* __restrict__ aS, const float* __restrict__ aD,
                const float* __restrict__ bias, const int* __restrict__ ro, const int* __restrict__ perm,
                u16* __restrict__ out)
{
  int wave = threadIdx.x>>6, lane = threadIdx.x&63;
  int node = blockIdx.x*4 + wave;
  if (node >= N_NODES) return;
  int h = lane >> 4, l = lane & 15;
  auto lk = [](float x){ return x>=0.f ? x : 0.2f*x; };
  float ad = aD[node*4+h];
  float sl = lk(aS[node*4+h] + ad);
  int beg = ro[node], end = ro[node+1];
  float m = sl;
  for (int j=beg; j<end; ++j)
    m = fmaxf(m, lk(aS[perm[j]*4+h] + ad));
  int fo = h*32 + l*2;
  float d, c0,c1;
  {
    float wv = __expf(sl - m);
    d = wv;
    unsigned int pv = *(const unsigned int*)(hb + (size_t)node*128 + fo);
    c0 = wv*b2f((u16)(pv & 0xffffu)); c1 = wv*b2f((u16)(pv >> 16));
  }
  for (int j=beg; j<end; ++j){
    int u = perm[j];
    float e = __expf(lk(aS[u*4+h] + ad) - m);
    d += e;
    unsigned int pv = *(const unsigned int*)(hb + (size_t)u*128 + fo);
    c0 += e*b2f((u16)(pv & 0xffffu)); c1 += e*b2f((u16)(pv >> 16));
  }
  float inv = 1.f/(d + 1e-16f);
  float o0 = c0*inv + bias[fo+0]; o0 = o0>0.f?o0:0.f;
  float o1 = c1*inv + bias[fo+1]; o1 = o1>0.f?o1:0.f;
  *(unsigned int*)(out + (size_t)node*128 + fo) = (unsigned int)f2b(o0) | ((unsigned int)f2b(o1)<<16);
}

// ---------------- transformer conv, head-parallel ----------------
// logits+max: 16 lanes per head, in-group 4-step reduction
__global__ __launch_bounds__(256)
void k_tr1(const u16* __restrict__ qb, const u16* __restrict__ kb,
           const int* __restrict__ ro, const int* __restrict__ perm,
           float* __restrict__ tlog, float* __restrict__ mbuf)
{
  int wave = threadIdx.x>>6, lane = threadIdx.x&63;
  int node = blockIdx.x*4 + wave;
  if (node >= N_NODES) return;
  int h = lane >> 4, l = lane & 15;
  int fo = h*64 + l*4;
  ushort4 qv = *(const ushort4*)(qb + (size_t)node*256 + fo);
  float q0=b2f(qv.x), q1=b2f(qv.y), q2=b2f(qv.z), q3=b2f(qv.w);
  float m = -INFINITY;
  int beg = ro[node], end = ro[node+1];
  for (int j=beg; j<end; ++j){
    int u = perm[j];
    ushort4 kv = *(const ushort4*)(kb + (size_t)u*256 + fo);
    float p = q0*b2f(kv.x) + q1*b2f(kv.y) + q2*b2f(kv.z) + q3*b2f(kv.w);
    p += __shfl_xor(p,1); p += __shfl_xor(p,2); p += __shfl_xor(p,4); p += __shfl_xor(p,8);
    p *= 0.125f;
    m = fmaxf(m, p);
    if (l==0) tlog[j*4+h] = p;
  }
  if (l==0) mbuf[node*4+h] = m;
}

// softmax-weighted V + head mean + skip + relu
__global__ __launch_bounds__(256)
void k_trans2(const u16* __restrict__ vb, const u16* __restrict__ skipb,
              const float* __restrict__ bsk,
              const int* __restrict__ ro, const int* __restrict__ perm,
              const float* __restrict__ tlog, const float* __restrict__ mbuf, u16* __restrict__ x4)
{
  int wave = threadIdx.x>>6, lane = threadIdx.x&63;
  int node = blockIdx.x*4 + wave;
  if (node >= N_NODES) return;
  int h = lane >> 4, l = lane & 15;
  int fo = h*64 + l*4;
  float m = mbuf[node*4+h];
  float d=0.f, a0=0.f,a1=0.f,a2=0.f,a3=0.f;
  int beg = ro[node], end = ro[node+1];
  for (int j=beg; j<end; ++j){
    int u = perm[j];
    float e = __expf(tlog[j*4+h] - m);
    d += e;
    ushort4 vv = *(const ushort4*)(vb + (size_t)u*256 + fo);
    a0 += e*b2f(vv.x); a1 += e*b2f(vv.y); a2 += e*b2f(vv.z); a3 += e*b2f(vv.w);
  }
  float inv = 0.25f/(d + 1e-16f);
  a0*=inv; a1*=inv; a2*=inv; a3*=inv;
  // mean over heads: butterfly across head groups (lanes differ in bits 4,5)
  a0 += __shfl_xor(a0,16); a0 += __shfl_xor(a0,32);
  a1 += __shfl_xor(a1,16); a1 += __shfl_xor(a1,32);
  a2 += __shfl_xor(a2,16); a2 += __shfl_xor(a2,32);
  a3 += __shfl_xor(a3,16); a3 += __shfl_xor(a3,32);
  if (h==0){
    int c = l*4;
    ushort4 sv = *(const ushort4*)(skipb + (size_t)node*64 + c);
    float o0 = a0 + b2f(sv.x) + bsk[c+0]; o0 = o0>0.f?o0:0.f;
    float o1 = a1 + b2f(sv.y) + bsk[c+1]; o1 = o1>0.f?o1:0.f;
    float o2 = a2 + b2f(sv.z) + bsk[c+2]; o2 = o2>0.f?o2:0.f;
    float o3 = a3 + b2f(sv.w) + bsk[c+3]; o3 = o3>0.f?o3:0.f;
    ushort4 ov = { f2b(o0), f2b(o1), f2b(o2), f2b(o3) };
    *(ushort4*)(x4 + (size_t)node*64 + c) = ov;
  }
}

// ---------------- final linear 64 -> 32, fp32 out ----------------
__global__ __launch_bounds__(256)
void k_final(const u16* __restrict__ x4, const float* __restrict__ Wf, const float* __restrict__ bf,
             float* __restrict__ out)
{
  int i = blockIdx.x*256+threadIdx.x;
  if (i >= N_NODES*32) return;
  int n = i>>5, c = i&31;
  const u16* xr = x4 + (size_t)n*64;
  float acc = 0.f;
  #pragma unroll
  for (int k=0;k<64;++k) acc += b2f(xr[k]) * Wf[k*32+c];
  acc += bf[c];
  out[i] = acc;
}

// ---------------- host ----------------
extern "C" void kernel_launch(void* const* d_in, const int* in_sizes, int n_in,
                              void* d_out, int out_size, void* d_ws, size_t ws_size,
                              hipStream_t stream)
{
  const float* i_x    = (const float*)d_in[0];
  const int*   i_ei   = (const int*)d_in[1];
  const float* i_cew  = (const float*)d_in[2];
  const float* i_cewW = (const float*)d_in[3];
  const float* i_cewB = (const float*)d_in[4];
  const float* i_cewA = (const float*)d_in[5];
  const float* i_W1   = (const float*)d_in[6];
  const float* i_aS1  = (const float*)d_in[7];
  const float* i_aD1  = (const float*)d_in[8];
  const float* i_b1   = (const float*)d_in[9];
  const float* i_W2   = (const float*)d_in[10];
  const float* i_aS2  = (const float*)d_in[11];
  const float* i_aD2  = (const float*)d_in[12];
  const float* i_b2   = (const float*)d_in[13];
  const float* i_Wq   = (const float*)d_in[14];
  const float* i_bq   = (const float*)d_in[15];
  const float* i_Wk   = (const float*)d_in[16];
  const float* i_bk   = (const float*)d_in[17];
  const float* i_Wv   = (const float*)d_in[18];
  const float* i_bv   = (const float*)d_in[19];
  const float* i_Wsk  = (const float*)d_in[20];
  const float* i_bsk  = (const float*)d_in[21];
  const float* i_Wf   = (const float*)d_in[22];
  const float* i_bf   = (const float*)d_in[23];
  (void)in_sizes; (void)n_in; (void)out_size;

  char* w = (char*)d_ws;
  size_t off = 0;
  auto A = [&](size_t bytes)->char*{ char* p = w + off; off = (off + bytes + 255) & ~(size_t)255; return p; };

  int*   bsums  = (int*)A(1024);
  float* sbuf   = (float*)A((size_t)N_NODES*4);
  float* aS     = (float*)A((size_t)N_NODES*16);
  float* aD     = (float*)A((size_t)N_NODES*16);
  float* mbuf   = (float*)A((size_t)N_NODES*16);
  int*   cnt    = (int*)A((size_t)N_NODES*4);
  int*   ro     = (int*)A((size_t)(N_NODES+1)*4);
  int*   cursor = (int*)A((size_t)N_NODES*4);
  int*   perm   = (int*)A((size_t)N_EDGES*4);
  float* tlog   = (float*)A((size_t)N_EDGES*16);
  u16*   cewWt  = (u16*)A(128*128*2);
  u16*   W1t    = (u16*)A(256*128*2);
  u16*   W2t    = (u16*)A(128*256*2);
  u16*   Wcat   = (u16*)A(896*128*2);
  u16*   xb     = (u16*)A((size_t)N_NODES*128*2);
  u16* S1 = (u16*)A((size_t)N_NODES*128*2);   // h0 -> h2 -> skipb(64-stride)
  u16* S2 = (u16*)A((size_t)N_NODES*128*2);   // x1 -> x3
  u16* G1 = (u16*)A((size_t)N_NODES*256*2);   // h1 -> qb -> vb
  u16* G2 = (u16*)A((size_t)N_NODES*256*2);   // x2 -> kb -> x4
  size_t need = off;

  float* outf = (float*)d_out;
  if (ws_size < need){
    k_fillf<<<(N_NODES*32+255)/256,256,0,stream>>>(outf, N_NODES*32,
        8192.f + 32.f * (float)((ws_size >> 20) > 255 ? 255 : (ws_size >> 20)));
    return;
  }

  u16* h0 = S1;  u16* x1 = S2;
  u16* h1 = G1;  u16* x2 = G2;
  u16* h2 = S1;  u16* x3 = S2;
  u16* qb = G1;  u16* kb = G2;
  u16* vb = G1;  u16* skipb = S1;  u16* x4 = G2;
  // NOTE: qkvs GEMM writes qb(G1),kb(G2),vb(G1)... conflict! vb shares G1 with qb.
  // Fix: vb gets its own region within S2 (x3 dead after qkvs GEMM reads it? NO - x3 is
  // the GEMM input). Use: qb=G1 (first half 25.6MB), vb=G1 second... G1 is 25.6MB = exactly
  // one 256-stride buffer. Allocate dedicated vbuf instead:
  u16* vbuf = (u16*)A((size_t)N_NODES*256*2);   // 25.6 MB extra
  need = off;
  if (ws_size < need){
    k_fillf<<<(N_NODES*32+255)/256,256,0,stream>>>(outf, N_NODES*32,
        8192.f + 32.f * (float)((ws_size >> 20) > 255 ? 255 : (ws_size >> 20)));
    return;
  }
  vb = vbuf;
  // x4 overlays kb(G2) — but k_trans2 reads tlog (not kb) and writes x4; kb dead after k_tr1. OK.

  k_zeroi<<<(N_NODES+255)/256,256,0,stream>>>(cnt, N_NODES);
  k_zeroi<<<(N_NODES+255)/256,256,0,stream>>>(cursor, N_NODES);

  // prep
  k_cvt_x<<<(N_NODES*128+255)/256,256,0,stream>>>(i_x, xb, N_NODES*128);
  k_transpose_b<<<(128*128+255)/256,256,0,stream>>>(i_cewW, cewWt, 128, 128, 128);
  k_transpose_b<<<(256*128+255)/256,256,0,stream>>>(i_W1,   W1t,  128, 256, 256);
  k_transpose_b<<<(128*256+255)/256,256,0,stream>>>(i_W2,   W2t,  256, 128, 128);
  k_transpose_cat<<<(896*128+255)/256,256,0,stream>>>(i_Wq, i_Wk, i_Wv, i_Wsk, Wcat);

  // CSR by destination
  k_count<<<(N_EDGES+255)/256,256,0,stream>>>(i_ei + N_EDGES, cnt);
  k_scan1<<<NBLK_SC,256,0,stream>>>(cnt, ro, bsums);
  k_scan2<<<1,256,0,stream>>>(bsums, NBLK_SC);
  k_scan3<<<NBLK_SC,256,0,stream>>>(ro, bsums);
  k_scatter<<<(N_EDGES+255)/256,256,0,stream>>>(i_ei, i_ei + N_EDGES, ro, cursor, perm);

  const int NAGG = (N_NODES+3)/4;
  const int NH4  = (N_NODES*4+255)/256;

  // layer 0: cew GAT
  k_gemm_mfma<<<MT128*1,256,0,stream>>>(xb, cewWt, i_cewB, h0, 128, 128, 1);
  k_rowdot_cew<<<(N_NODES+255)/256,256,0,stream>>>(h0, i_cewA, sbuf);
  k_agg_cew<<<NAGG,256,0,stream>>>(h0, sbuf, i_cew, ro, perm, x1);

  // layer 1: GAT(128 -> 4x64)
  k_gemm_mfma<<<MT128*2,256,0,stream>>>(x1, W1t, nullptr, h1, 128, 256, 2);
  k_rowdot4<<<NH4,256,0,stream>>>(h1, i_aS1, i_aD1, aS, aD);
  k_agg_gat1<<<NAGG,256,0,stream>>>(h1, aS, aD, i_b1, ro, perm, x2);

  // layer 2: GAT(256 -> 4x32)
  k_gemm_mfma<<<MT128*1,256,0,stream>>>(x2, W2t, nullptr, h2, 256, 128, 1);
  k_rowdot2<<<NH4,256,0,stream>>>(h2, i_aS2, i_aD2, aS, aD);
  k_agg_gat2<<<NAGG,256,0,stream>>>(h2, aS, aD, i_b2, ro, perm, x3);

  // layer 3: transformer conv (fused q|k|v|skip GEMM)
  k_gemm_qkvs<<<MT128*7,256,0,stream>>>(x3, Wcat, i_bq, i_bk, i_bv, qb, kb, vb, skipb);
  k_tr1<<<NAGG,256,0,stream>>>(qb, kb, ro, perm, tlog, mbuf);
  k_trans2<<<NAGG,256,0,stream>>>(vb, skipb, i_bsk, ro, perm, tlog, mbuf, x4);

  // final linear (fp32 out)
  k_final<<<(N_NODES*32+255)/256,256,0,stream>>>(x4, i_Wf, i_bf, outf);
}

// Round 11
// 563.930 us; speedup vs baseline: 2.2269x; 1.2199x over previous
//
#include <hip/hip_runtime.h>
#include <stdint.h>

#define N_NODES 50000
#define N_EDGES 400000
#define NBLK_SC 196        // ceil(50000/256)
#define MT128   391        // ceil(50000/128) m-tiles

typedef unsigned short u16;
typedef __attribute__((ext_vector_type(8))) short short8;
typedef __attribute__((ext_vector_type(4))) float f32x4;

__device__ __forceinline__ float b2f(u16 u){ unsigned int x=((unsigned int)u)<<16; float f; __builtin_memcpy(&f,&x,4); return f; }
__device__ __forceinline__ u16 f2b(float f){ unsigned int x; __builtin_memcpy(&x,&f,4); x += 0x7fffu + ((x>>16)&1u); return (u16)(x>>16); }

// ---------------- utility ----------------
__global__ void k_zeroi(int* __restrict__ p, int n){
  int i = blockIdx.x*256+threadIdx.x;
  if (i < n) p[i] = 0;
}
__global__ void k_fillf(float* __restrict__ p, int n, float v){
  int i = blockIdx.x*256+threadIdx.x;
  if (i < n) p[i] = v;
}
__global__ void k_cvt_x(const float* __restrict__ x, u16* __restrict__ xb, int n){
  int i = blockIdx.x*256+threadIdx.x;
  if (i < n) xb[i] = f2b(x[i]);
}
// Wt[n*K+k] = bf16(W[k*Nc+n]), zero-pad n in [Nc,Npad)
__global__ void k_transpose_b(const float* __restrict__ W, u16* __restrict__ Wt, int K, int Nc, int Npad){
  int i = blockIdx.x*256+threadIdx.x;
  if (i >= Npad*K) return;
  int n = i / K, k = i - n*K;
  Wt[i] = (n < Nc) ? f2b(W[k*Nc + n]) : (u16)0;
}
// concatenated transpose for q|k|v|skip, Wt[896*128]
__global__ void k_transpose_cat(const float* __restrict__ Wq, const float* __restrict__ Wk,
                                const float* __restrict__ Wv, const float* __restrict__ Wsk,
                                u16* __restrict__ Wt){
  int i = blockIdx.x*256+threadIdx.x;
  if (i >= 896*128) return;
  int n = i >> 7, k = i & 127;
  float v = 0.f;
  if      (n < 256) v = Wq[k*256 + n];
  else if (n < 512) v = Wk[k*256 + (n-256)];
  else if (n < 768) v = Wv[k*256 + (n-512)];
  else if (n < 832) v = Wsk[k*64 + (n-768)];
  Wt[i] = f2b(v);
}

// ---------------- CSR build ----------------
__global__ void k_count(const int* __restrict__ dst, int* __restrict__ cnt){
  int e = blockIdx.x*256+threadIdx.x;
  if (e < N_EDGES) atomicAdd(&cnt[dst[e]], 1);
}
__global__ void k_scan1(const int* __restrict__ cnt, int* __restrict__ ro, int* __restrict__ bsums){
  __shared__ int sm[256];
  int b = blockIdx.x, t = threadIdx.x, i = b*256+t;
  int v = (i < N_NODES) ? cnt[i] : 0;
  sm[t] = v; __syncthreads();
  for (int off=1; off<256; off<<=1){
    int x = 0; if (t>=off) x = sm[t-off];
    __syncthreads();
    if (t>=off) sm[t] += x;
    __syncthreads();
  }
  if (i < N_NODES) ro[i] = sm[t]-v;
  if (t==255) bsums[b] = sm[255];
}
__global__ void k_scan2(int* __restrict__ bsums, int nb){
  __shared__ int sm[256];
  int t = threadIdx.x;
  int v = (t<nb) ? bsums[t] : 0;
  sm[t]=v; __syncthreads();
  for (int off=1; off<256; off<<=1){
    int x = 0; if (t>=off) x = sm[t-off];
    __syncthreads();
    if (t>=off) sm[t] += x;
    __syncthreads();
  }
  if (t<nb) bsums[t] = sm[t]-v;
}
__global__ void k_scan3(int* __restrict__ ro, const int* __restrict__ bsums){
  int b = blockIdx.x, t = threadIdx.x, i = b*256+t;
  if (i < N_NODES) ro[i] += bsums[b];
  if (i == 0) ro[N_NODES] = N_EDGES;
}
__global__ void k_scatter(const int* __restrict__ src, const int* __restrict__ dst,
                          const int* __restrict__ ro, int* __restrict__ cursor,
                          int* __restrict__ perm){
  int e = blockIdx.x*256+threadIdx.x;
  if (e >= N_EDGES) return;
  int d = dst[e];
  int pos = ro[d] + atomicAdd(&cursor[d], 1);
  perm[pos] = src[e];
}

// ---------------- MFMA GEMM: C[N x Nst] = A[N x K] @ Bt^T + bias ----------------
__global__ __launch_bounds__(256)
void k_gemm_mfma(const u16* __restrict__ A, const u16* __restrict__ Bt,
                 const float* __restrict__ bias, u16* __restrict__ C,
                 int K, int Nst, int nTiles)
{
  __shared__ u16 sA[128][40];
  __shared__ u16 sB[128][40];
  int t = threadIdx.x, lane = t & 63, wave = t >> 6;
  int wr = wave >> 1, wc = wave & 1;
  int mTile = blockIdx.x / nTiles, nTile = blockIdx.x - mTile*nTiles;
  int mBase = mTile*128, nBase = nTile*128;
  f32x4 acc[4][4] = {};
  const int row = lane & 15, kq = (lane >> 4) * 8;
  for (int k0 = 0; k0 < K; k0 += 32){
    #pragma unroll
    for (int it = 0; it < 2; ++it){
      int c = it*256 + t;
      int m = c >> 2, ko = (c & 3) * 8;
      int ra = mBase + m;
      uint4 va = {0u,0u,0u,0u};
      if (ra < N_NODES) va = *(const uint4*)(A + (size_t)ra*K + k0 + ko);
      *(uint4*)&sA[m][ko] = va;
      *(uint4*)&sB[m][ko] = *(const uint4*)(Bt + (size_t)(nBase+m)*K + k0 + ko);
    }
    __syncthreads();
    short8 af[4], bfr[4];
    #pragma unroll
    for (int i=0;i<4;i++) af[i]  = *(const short8*)&sA[wr*64 + i*16 + row][kq];
    #pragma unroll
    for (int i=0;i<4;i++) bfr[i] = *(const short8*)&sB[wc*64 + i*16 + row][kq];
    #pragma unroll
    for (int i=0;i<4;i++)
      #pragma unroll
      for (int j=0;j<4;j++)
        acc[i][j] = __builtin_amdgcn_mfma_f32_16x16x32_bf16(af[i], bfr[j], acc[i][j], 0,0,0);
    __syncthreads();
  }
  #pragma unroll
  for (int i=0;i<4;i++)
    #pragma unroll
    for (int j=0;j<4;j++)
      #pragma unroll
      for (int r=0;r<4;r++){
        int mm = mBase + wr*64 + i*16 + (lane>>4)*4 + r;
        if (mm >= N_NODES) continue;
        int nn = nBase + wc*64 + j*16 + (lane&15);
        float v = acc[i][j][r];
        if (bias) v += bias[nn];
        C[(size_t)mm*Nst + nn] = f2b(v);
      }
}

// fused q|k|v|skip GEMM: K=128, 896 output cols routed to 4 buffers
__global__ __launch_bounds__(256)
void k_gemm_qkvs(const u16* __restrict__ A, const u16* __restrict__ Bt,
                 const float* __restrict__ bq, const float* __restrict__ bk,
                 const float* __restrict__ bv,
                 u16* __restrict__ qb, u16* __restrict__ kb, u16* __restrict__ vb,
                 u16* __restrict__ skipb)
{
  __shared__ u16 sA[128][40];
  __shared__ u16 sB[128][40];
  int t = threadIdx.x, lane = t & 63, wave = t >> 6;
  int wr = wave >> 1, wc = wave & 1;
  int mTile = blockIdx.x / 7, nTile = blockIdx.x - mTile*7;
  int mBase = mTile*128, nBase = nTile*128;
  f32x4 acc[4][4] = {};
  const int row = lane & 15, kq = (lane >> 4) * 8;
  const int K = 128;
  for (int k0 = 0; k0 < K; k0 += 32){
    #pragma unroll
    for (int it = 0; it < 2; ++it){
      int c = it*256 + t;
      int m = c >> 2, ko = (c & 3) * 8;
      int ra = mBase + m;
      uint4 va = {0u,0u,0u,0u};
      if (ra < N_NODES) va = *(const uint4*)(A + (size_t)ra*K + k0 + ko);
      *(uint4*)&sA[m][ko] = va;
      *(uint4*)&sB[m][ko] = *(const uint4*)(Bt + (size_t)(nBase+m)*K + k0 + ko);
    }
    __syncthreads();
    short8 af[4], bfr[4];
    #pragma unroll
    for (int i=0;i<4;i++) af[i]  = *(const short8*)&sA[wr*64 + i*16 + row][kq];
    #pragma unroll
    for (int i=0;i<4;i++) bfr[i] = *(const short8*)&sB[wc*64 + i*16 + row][kq];
    #pragma unroll
    for (int i=0;i<4;i++)
      #pragma unroll
      for (int j=0;j<4;j++)
        acc[i][j] = __builtin_amdgcn_mfma_f32_16x16x32_bf16(af[i], bfr[j], acc[i][j], 0,0,0);
    __syncthreads();
  }
  #pragma unroll
  for (int j=0;j<4;j++){
    int nn = nBase + wc*64 + j*16 + (lane&15);
    u16* dst; int stride, col; float bias;
    if      (nn < 256){ dst=qb;    stride=256; col=nn;     bias=bq[nn];     }
    else if (nn < 512){ dst=kb;    stride=256; col=nn-256; bias=bk[nn-256]; }
    else if (nn < 768){ dst=vb;    stride=256; col=nn-512; bias=bv[nn-512]; }
    else if (nn < 832){ dst=skipb; stride=64;  col=nn-768; bias=0.f;        }
    else continue;
    #pragma unroll
    for (int i=0;i<4;i++)
      #pragma unroll
      for (int r=0;r<4;r++){
        int mm = mBase + wr*64 + i*16 + (lane>>4)*4 + r;
        if (mm >= N_NODES) continue;
        dst[(size_t)mm*stride + col] = f2b(acc[i][j][r] + bias);
      }
  }
}

// ---------------- row-dots (thread-serial) ----------------
__global__ __launch_bounds__(256)
void k_rowdot_cew(const u16* __restrict__ hb, const float* __restrict__ att, float* __restrict__ s){
  int n = blockIdx.x*256+threadIdx.x;
  if (n >= N_NODES) return;
  const u16* hp = hb + (size_t)n*128;
  float acc = 0.f;
  #pragma unroll 8
  for (int c=0;c<128;++c) acc += b2f(hp[c])*att[c];
  s[n] = acc;
}
__global__ __launch_bounds__(256)
void k_rowdot4(const u16* __restrict__ hb, const float* __restrict__ attS, const float* __restrict__ attD,
               float* __restrict__ aS, float* __restrict__ aD){
  int t = blockIdx.x*256+threadIdx.x;
  if (t >= N_NODES*4) return;
  int n = t>>2, h = t&3;
  const u16* hp = hb + (size_t)n*256 + h*64;
  const float* as = attS + h*64;
  const float* ad = attD + h*64;
  float ps=0.f, pd=0.f;
  #pragma unroll 8
  for (int c=0;c<64;++c){ float v=b2f(hp[c]); ps += v*as[c]; pd += v*ad[c]; }
  aS[t]=ps; aD[t]=pd;
}
__global__ __launch_bounds__(256)
void k_rowdot2(const u16* __restrict__ hb, const float* __restrict__ attS, const float* __restrict__ attD,
               float* __restrict__ aS, float* __restrict__ aD){
  int t = blockIdx.x*256+threadIdx.x;
  if (t >= N_NODES*4) return;
  int n = t>>2, h = t&3;
  const u16* hp = hb + (size_t)n*128 + h*32;
  const float* as = attS + h*32;
  const float* ad = attD + h*32;
  float ps=0.f, pd=0.f;
  #pragma unroll 8
  for (int c=0;c<32;++c){ float v=b2f(hp[c]); ps += v*as[c]; pd += v*ad[c]; }
  aS[t]=ps; aD[t]=pd;
}

// ---------------- layer-0 aggregation: online softmax, 64-lane chunks ----------------
__global__ __launch_bounds__(256)
void k_agg_cew(const u16* __restrict__ h0, const float* __restrict__ s, const float* __restrict__ cewf,
               const int* __restrict__ ro, const int* __restrict__ perm, u16* __restrict__ x1)
{
  int wave = threadIdx.x>>6, lane = threadIdx.x&63;
  int node = blockIdx.x*4 + wave;
  if (node >= N_NODES) return;
  float sd = s[node], cd = cewf[node];
  int beg = ro[node], end = ro[node+1];
  int f = 2*lane;
  float m = -INFINITY, d = 0.f, a0 = 0.f, a1 = 0.f;
  for (int cbeg = beg; cbeg < end; cbeg += 64){
    int j = cbeg + lane;
    float lg = -INFINITY; int u = 0;
    if (j < end){
      u = perm[j];
      float a = s[u] + sd; a = a>=0.f ? a : 0.01f*a;
      lg = a * (cewf[u] + cd);
    }
    float cm = lg;
    #pragma unroll
    for (int o=32;o;o>>=1) cm = fmaxf(cm, __shfl_xor(cm,o));
    if (cm > m){
      float r = __expf(m - cm);
      d*=r; a0*=r; a1*=r; m = cm;
    }
    float wl = __expf(lg - m);
    int cnt = end - cbeg; if (cnt > 64) cnt = 64;
    for (int e=0; e<cnt; ++e){
      float we = __shfl(wl, e);
      int ue = __shfl(u, e);
      d += we;
      unsigned int pv = *(const unsigned int*)(h0 + (size_t)ue*128 + f);
      a0 += we * b2f((u16)(pv & 0xffffu));
      a1 += we * b2f((u16)(pv >> 16));
    }
  }
  float inv = 1.f/(d + 1e-16f);
  float o0 = a0*inv; o0 = o0>0.f?o0:0.f;
  float o1 = a1*inv; o1 = o1>0.f?o1:0.f;
  *(unsigned int*)(x1 + (size_t)node*128 + f) = (unsigned int)f2b(o0) | ((unsigned int)f2b(o1)<<16);
}

// ---------------- GAT aggregation, head-parallel + online softmax ----------------
// layer 1: F=256, C=64 -> lane h*16+l owns out channels h*64 + 4l..4l+3
__global__ __launch_bounds__(256)
void k_agg_gat1(const u16* __restrict__ hb, const float* __restrict__ aS, const float* __restrict__ aD,
                const float* __restrict__ bias, const int* __restrict__ ro, const int* __restrict__ perm,
                u16* __restrict__ out)
{
  int wave = threadIdx.x>>6, lane = threadIdx.x&63;
  int node = blockIdx.x*4 + wave;
  if (node >= N_NODES) return;
  int h = lane >> 4, l = lane & 15, grp = h << 4;
  auto lk = [](float x){ return x>=0.f ? x : 0.2f*x; };
  float ad = aD[node*4+h];
  float sl = lk(aS[node*4+h] + ad);
  int beg = ro[node], end = ro[node+1];
  int fo = h*64 + l*4;
  float m = sl, d = 1.f;   // self-loop weight exp(sl-m)=1
  float c0,c1,c2,c3;
  { ushort4 pv = *(const ushort4*)(hb + (size_t)node*256 + fo);
    c0=b2f(pv.x); c1=b2f(pv.y); c2=b2f(pv.z); c3=b2f(pv.w); }
  for (int cbeg = beg; cbeg < end; cbeg += 16){
    int j = cbeg + l;
    float lg = -INFINITY; int u = 0;
    if (j < end){ u = perm[j]; lg = lk(aS[u*4+h] + ad); }
    float cm = lg;
    cm = fmaxf(cm, __shfl_xor(cm,1));
    cm = fmaxf(cm, __shfl_xor(cm,2));
    cm = fmaxf(cm, __shfl_xor(cm,4));
    cm = fmaxf(cm, __shfl_xor(cm,8));
    if (cm > m){
      float r = __expf(m - cm);
      d*=r; c0*=r; c1*=r; c2*=r; c3*=r; m = cm;
    }
    float wl = __expf(lg - m);
    int cnt = end - cbeg; if (cnt > 16) cnt = 16;
    for (int e=0; e<cnt; ++e){
      float we = __shfl(wl, grp + e);
      int ue = __shfl(u, grp + e);
      d += we;
      ushort4 vv = *(const ushort4*)(hb + (size_t)ue*256 + fo);
      c0 += we*b2f(vv.x); c1 += we*b2f(vv.y); c2 += we*b2f(vv.z); c3 += we*b2f(vv.w);
    }
  }
  float inv = 1.f/(d + 1e-16f);
  float o0 = c0*inv + bias[fo+0]; o0 = o0>0.f?o0:0.f;
  float o1 = c1*inv + bias[fo+1]; o1 = o1>0.f?o1:0.f;
  float o2 = c2*inv + bias[fo+2]; o2 = o2>0.f?o2:0.f;
  float o3 = c3*inv + bias[fo+3]; o3 = o3>0.f?o3:0.f;
  ushort4 ov = { f2b(o0), f2b(o1), f2b(o2), f2b(o3) };
  *(ushort4*)(out + (size_t)node*256 + fo) = ov;
}

// layer 2: F=128, C=32 -> lane h*16+l owns out channels h*32 + 2l..2l+1
__global__ __launch_bounds__(256)
void k_agg_gat2(const u16* __restrict__ hb, const float* __restrict__ aS, const float* __restrict__ aD,
                const float* __restrict__ bias, const int* __restrict__ ro, const int* __restrict__ perm,
                u16* __restrict__ out)
{
  int wave = threadIdx.x>>6, lane = threadIdx.x&63;
  int node = blockIdx.x*4 + wave;
  if (node >= N_NODES) return;
  int h = lane >> 4, l = lane & 15, grp = h << 4;
  auto lk = [](float x){ return x>=0.f ? x : 0.2f*x; };
  float ad = aD[node*4+h];
  float sl = lk(aS[node*4+h] + ad);
  int beg = ro[node], end = ro[node+1];
  int fo = h*32 + l*2;
  float m = sl, d = 1.f;
  float c0,c1;
  { unsigned int pv = *(const unsigned int*)(hb + (size_t)node*128 + fo);
    c0 = b2f((u16)(pv & 0xffffu)); c1 = b2f((u16)(pv >> 16)); }
  for (int cbeg = beg; cbeg < end; cbeg += 16){
    int j = cbeg + l;
    float lg = -INFINITY; int u = 0;
    if (j < end){ u = perm[j]; lg = lk(aS[u*4+h] + ad); }
    float cm = lg;
    cm = fmaxf(cm, __shfl_xor(cm,1));
    cm = fmaxf(cm, __shfl_xor(cm,2));
    cm = fmaxf(cm, __shfl_xor(cm,4));
    cm = fmaxf(cm, __shfl_xor(cm,8));
    if (cm > m){
      float r = __expf(m - cm);
      d*=r; c0*=r; c1*=r; m = cm;
    }
    float wl = __expf(lg - m);
    int cnt = end - cbeg; if (cnt > 16) cnt = 16;
    for (int e=0; e<cnt; ++e){
      float we = __shfl(wl, grp + e);
      int ue = __shfl(u, grp + e);
      d += we;
      unsigned int pv = *(const unsigned int*)(hb + (size_t)ue*128 + fo);
      c0 += we*b2f((u16)(pv & 0xffffu));
      c1 += we*b2f((u16)(pv >> 16));
    }
  }
  float inv = 1.f/(d + 1e-16f);
  float o0 = c0*inv + bias[fo+0]; o0 = o0>0.f?o0:0.f;
  float o1 = c1*inv + bias[fo+1]; o1 = o1>0.f?o1:0.f;
  *(unsigned int*)(out + (size_t)node*128 + fo) = (unsigned int)f2b(o0) | ((unsigned int)f2b(o1)<<16);
}

// ---------------- transformer conv: fused online-softmax attention ----------------
__global__ __launch_bounds__(256)
void k_tr(const u16* __restrict__ qb, const u16* __restrict__ kb, const u16* __restrict__ vb,
          const u16* __restrict__ skipb, const float* __restrict__ bsk,
          const int* __restrict__ ro, const int* __restrict__ perm, u16* __restrict__ x4)
{
  int wave = threadIdx.x>>6, lane = threadIdx.x&63;
  int node = blockIdx.x*4 + wave;
  if (node >= N_NODES) return;
  int h = lane >> 4, l = lane & 15;
  int fo = h*64 + l*4;
  ushort4 qv = *(const ushort4*)(qb + (size_t)node*256 + fo);
  float q0=b2f(qv.x), q1=b2f(qv.y), q2=b2f(qv.z), q3=b2f(qv.w);
  float m=-INFINITY, d=0.f, a0=0.f,a1=0.f,a2=0.f,a3=0.f;
  int beg = ro[node], end = ro[node+1];
  for (int j=beg; j<end; ++j){
    int u = perm[j];
    ushort4 kv = *(const ushort4*)(kb + (size_t)u*256 + fo);
    float p = q0*b2f(kv.x) + q1*b2f(kv.y) + q2*b2f(kv.z) + q3*b2f(kv.w);
    p += __shfl_xor(p,1); p += __shfl_xor(p,2); p += __shfl_xor(p,4); p += __shfl_xor(p,8);
    p *= 0.125f;
    if (p > m){
      float r = __expf(m - p);   // first iter: exp(-inf)=0, accs are 0
      d*=r; a0*=r; a1*=r; a2*=r; a3*=r; m = p;
    }
    float w = __expf(p - m);
    d += w;
    ushort4 vv = *(const ushort4*)(vb + (size_t)u*256 + fo);
    a0 += w*b2f(vv.x); a1 += w*b2f(vv.y); a2 += w*b2f(vv.z); a3 += w*b2f(vv.w);
  }
  float inv = 0.25f/(d + 1e-16f);
  a0*=inv; a1*=inv; a2*=inv; a3*=inv;
  a0 += __shfl_xor(a0,16); a0 += __shfl_xor(a0,32);
  a1 += __shfl_xor(a1,16); a1 += __shfl_xor(a1,32);
  a2 += __shfl_xor(a2,16); a2 += __shfl_xor(a2,32);
  a3 += __shfl_xor(a3,16); a3 += __shfl_xor(a3,32);
  if (h==0){
    int c = l*4;
    ushort4 sv = *(const ushort4*)(skipb + (size_t)node*64 + c);
    float o0 = a0 + b2f(sv.x) + bsk[c+0]; o0 = o0>0.f?o0:0.f;
    float o1 = a1 + b2f(sv.y) + bsk[c+1]; o1 = o1>0.f?o1:0.f;
    float o2 = a2 + b2f(sv.z) + bsk[c+2]; o2 = o2>0.f?o2:0.f;
    float o3 = a3 + b2f(sv.w) + bsk[c+3]; o3 = o3>0.f?o3:0.f;
    ushort4 ov = { f2b(o0), f2b(o1), f2b(o2), f2b(o3) };
    *(ushort4*)(x4 + (size_t)node*64 + c) = ov;
  }
}

// ---------------- final linear 64 -> 32, fp32 out ----------------
__global__ __launch_bounds__(256)
void k_final(const u16* __restrict__ x4, const float* __restrict__ Wf, const float* __restrict__ bf,
             float* __restrict__ out)
{
  int i = blockIdx.x*256+threadIdx.x;
  if (i >= N_NODES*32) return;
  int n = i>>5, c = i&31;
  const u16* xr = x4 + (size_t)n*64;
  float acc = 0.f;
  #pragma unroll
  for (int k=0;k<64;++k) acc += b2f(xr[k]) * Wf[k*32+c];
  acc += bf[c];
  out[i] = acc;
}

// ---------------- host ----------------
extern "C" void kernel_launch(void* const* d_in, const int* in_sizes, int n_in,
                              void* d_out, int out_size, void* d_ws, size_t ws_size,
                              hipStream_t stream)
{
  const float* i_x    = (const float*)d_in[0];
  const int*   i_ei   = (const int*)d_in[1];
  const float* i_cew  = (const float*)d_in[2];
  const float* i_cewW = (const float*)d_in[3];
  const float* i_cewB = (const float*)d_in[4];
  const float* i_cewA = (const float*)d_in[5];
  const float* i_W1   = (const float*)d_in[6];
  const float* i_aS1  = (const float*)d_in[7];
  const float* i_aD1  = (const float*)d_in[8];
  const float* i_b1   = (const float*)d_in[9];
  const float* i_W2   = (const float*)d_in[10];
  const float* i_aS2  = (const float*)d_in[11];
  const float* i_aD2  = (const float*)d_in[12];
  const float* i_b2   = (const float*)d_in[13];
  const float* i_Wq   = (const float*)d_in[14];
  const float* i_bq   = (const float*)d_in[15];
  const float* i_Wk   = (const float*)d_in[16];
  const float* i_bk   = (const float*)d_in[17];
  const float* i_Wv   = (const float*)d_in[18];
  const float* i_bv   = (const float*)d_in[19];
  const float* i_Wsk  = (const float*)d_in[20];
  const float* i_bsk  = (const float*)d_in[21];
  const float* i_Wf   = (const float*)d_in[22];
  const float* i_bf   = (const float*)d_in[23];
  (void)in_sizes; (void)n_in; (void)out_size;

  char* w = (char*)d_ws;
  size_t off = 0;
  auto A = [&](size_t bytes)->char*{ char* p = w + off; off = (off + bytes + 255) & ~(size_t)255; return p; };

  int*   bsums  = (int*)A(1024);
  float* sbuf   = (float*)A((size_t)N_NODES*4);
  float* aS     = (float*)A((size_t)N_NODES*16);
  float* aD     = (float*)A((size_t)N_NODES*16);
  int*   cnt    = (int*)A((size_t)N_NODES*4);
  int*   ro     = (int*)A((size_t)(N_NODES+1)*4);
  int*   cursor = (int*)A((size_t)N_NODES*4);
  int*   perm   = (int*)A((size_t)N_EDGES*4);
  u16*   cewWt  = (u16*)A(128*128*2);
  u16*   W1t    = (u16*)A(256*128*2);
  u16*   W2t    = (u16*)A(128*256*2);
  u16*   Wcat   = (u16*)A(896*128*2);
  u16*   xb     = (u16*)A((size_t)N_NODES*128*2);
  u16* S1   = (u16*)A((size_t)N_NODES*128*2);   // h0 -> h2 -> skipb(64-stride)
  u16* S2   = (u16*)A((size_t)N_NODES*128*2);   // x1 -> x3
  u16* G1   = (u16*)A((size_t)N_NODES*256*2);   // h1 -> qb
  u16* G2   = (u16*)A((size_t)N_NODES*256*2);   // x2 -> kb -> x4
  u16* G3   = (u16*)A((size_t)N_NODES*256*2);   // vb
  size_t need = off;

  float* outf = (float*)d_out;
  if (ws_size < need){
    k_fillf<<<(N_NODES*32+255)/256,256,0,stream>>>(outf, N_NODES*32,
        8192.f + 32.f * (float)((ws_size >> 20) > 255 ? 255 : (ws_size >> 20)));
    return;
  }

  u16* h0 = S1;  u16* x1 = S2;
  u16* h1 = G1;  u16* x2 = G2;
  u16* h2 = S1;  u16* x3 = S2;
  u16* qb = G1;  u16* kb = G2;  u16* vb = G3;
  u16* skipb = S1;  u16* x4 = S2;   // x3 dead after qkvs GEMM; x4 overlays it

  k_zeroi<<<(N_NODES+255)/256,256,0,stream>>>(cnt, N_NODES);
  k_zeroi<<<(N_NODES+255)/256,256,0,stream>>>(cursor, N_NODES);

  // prep
  k_cvt_x<<<(N_NODES*128+255)/256,256,0,stream>>>(i_x, xb, N_NODES*128);
  k_transpose_b<<<(128*128+255)/256,256,0,stream>>>(i_cewW, cewWt, 128, 128, 128);
  k_transpose_b<<<(256*128+255)/256,256,0,stream>>>(i_W1,   W1t,  128, 256, 256);
  k_transpose_b<<<(128*256+255)/256,256,0,stream>>>(i_W2,   W2t,  256, 128, 128);
  k_transpose_cat<<<(896*128+255)/256,256,0,stream>>>(i_Wq, i_Wk, i_Wv, i_Wsk, Wcat);

  // CSR by destination
  k_count<<<(N_EDGES+255)/256,256,0,stream>>>(i_ei + N_EDGES, cnt);
  k_scan1<<<NBLK_SC,256,0,stream>>>(cnt, ro, bsums);
  k_scan2<<<1,256,0,stream>>>(bsums, NBLK_SC);
  k_scan3<<<NBLK_SC,256,0,stream>>>(ro, bsums);
  k_scatter<<<(N_EDGES+255)/256,256,0,stream>>>(i_ei, i_ei + N_EDGES, ro, cursor, perm);

  const int NAGG = (N_NODES+3)/4;
  const int NH4  = (N_NODES*4+255)/256;

  // layer 0: cew GAT
  k_gemm_mfma<<<MT128*1,256,0,stream>>>(xb, cewWt, i_cewB, h0, 128, 128, 1);
  k_rowdot_cew<<<(N_NODES+255)/256,256,0,stream>>>(h0, i_cewA, sbuf);
  k_agg_cew<<<NAGG,256,0,stream>>>(h0, sbuf, i_cew, ro, perm, x1);

  // layer 1: GAT(128 -> 4x64)
  k_gemm_mfma<<<MT128*2,256,0,stream>>>(x1, W1t, nullptr, h1, 128, 256, 2);
  k_rowdot4<<<NH4,256,0,stream>>>(h1, i_aS1, i_aD1, aS, aD);
  k_agg_gat1<<<NAGG,256,0,stream>>>(h1, aS, aD, i_b1, ro, perm, x2);

  // layer 2: GAT(256 -> 4x32)
  k_gemm_mfma<<<MT128*1,256,0,stream>>>(x2, W2t, nullptr, h2, 256, 128, 1);
  k_rowdot2<<<NH4,256,0,stream>>>(h2, i_aS2, i_aD2, aS, aD);
  k_agg_gat2<<<NAGG,256,0,stream>>>(h2, aS, aD, i_b2, ro, perm, x3);

  // layer 3: transformer conv (fused GEMM + fused online-softmax attention)
  k_gemm_qkvs<<<MT128*7,256,0,stream>>>(x3, Wcat, i_bq, i_bk, i_bv, qb, kb, vb, skipb);
  k_tr<<<NAGG,256,0,stream>>>(qb, kb, vb, skipb, i_bsk, ro, perm, x4);

  // final linear (fp32 out)
  k_final<<<(N_NODES*32+255)/256,256,0,stream>>>(x4, i_Wf, i_bf, outf);
}